// Round 4
// baseline (167.881 us; speedup 1.0000x reference)
//
#include <hip/hip_runtime.h>
#include <hip/hip_bf16.h>
#include <hip/hip_fp16.h>
#include <math.h>

#define BATCH   2
#define SEQ     4096
#define DIM     1024
#define HEADS   16
#define DSTATE  64
#define HEADDIM 64
#define BLOCKL  64
#define NCHUNK  64
#define ROWS    (BATCH*SEQ)

typedef __attribute__((ext_vector_type(4))) float f32x4;
typedef __attribute__((ext_vector_type(8))) short bf16x8;
typedef __attribute__((ext_vector_type(2))) _Float16 f16x2;

static __device__ __forceinline__ float softplus_f(float x){
    return (x > 20.f) ? x : log1pf(__expf(x));
}
static __device__ __forceinline__ ushort f2b(float f){
    __hip_bfloat16 h = __float2bfloat16(f);
    return *reinterpret_cast<ushort*>(&h);
}
static __device__ __forceinline__ float fdot2u(uint a, uint b, float c){
#if __has_builtin(__builtin_amdgcn_fdot2)
    union { uint u; f16x2 h; } ua, ub; ua.u = a; ub.u = b;
    return __builtin_amdgcn_fdot2(ua.h, ub.h, c, false);
#else
    union { uint u; __half2 h; } ua, ub; ua.u = a; ub.u = b;
    float2 fa = __half22float2(ua.h), fb = __half22float2(ub.h);
    return c + fa.x*fb.x + fa.y*fb.y;
#endif
}
static __device__ __forceinline__ void gload16(const void* g, void* l){
    __builtin_amdgcn_global_load_lds((const __attribute__((address_space(1))) unsigned int*)g,
                                     (__attribute__((address_space(3))) unsigned int*)l, 16, 0, 0);
}

// ---------------------------------------------------------------------------
// K1: dt = softplus(X@W_dt + bias); dtA = -exp(a_log)*dt
__global__ __launch_bounds__(256) void k_dt(const float* __restrict__ X,
        const float* __restrict__ Wdt, const float* __restrict__ dtb,
        const float* __restrict__ alog,
        float* __restrict__ dt_g, float* __restrict__ dtA_g){
    int r = blockIdx.x;
    int s = r & (SEQ-1);
    int tid = threadIdx.x;
    __shared__ float xrow[DIM];
    __shared__ float red[16][17];
    *(f32x4*)(xrow + tid*4) = *(const f32x4*)(X + (size_t)r*DIM + tid*4);
    __syncthreads();
    int part = tid >> 4, h = tid & 15;
    int d0 = part * 64;
    float acc = 0.f;
    #pragma unroll 8
    for (int i = 0; i < 64; ++i)
        acc += xrow[d0 + i] * Wdt[(size_t)(d0 + i)*HEADS + h];
    red[part][h] = acc;
    __syncthreads();
    if (tid < 16){
        float sum = 0.f;
        #pragma unroll
        for (int p = 0; p < 16; ++p) sum += red[p][tid];
        sum += dtb[(size_t)s*HEADS + tid];
        float dtv = softplus_f(sum);
        dt_g[(size_t)r*HEADS + tid]  = dtv;
        dtA_g[(size_t)r*HEADS + tid] = -__expf(alog[tid]) * dtv;
    }
}

// ---------------------------------------------------------------------------
// K2 (MFMA, round-2-verified dataflow): G=C·B^T -> M ; Y_diag=M·Xd ;
//   chunk_state = (w·Xd)^T·B.  Transposed tiles built via in-LDS u16 scatter
//   from register-resident row data (no strided global loads, no tr-reads).
__global__ __launch_bounds__(256) void k_chunk(const float* __restrict__ X,
        const float* __restrict__ Bin, const float* __restrict__ Cin,
        const float* __restrict__ dt_g, const float* __restrict__ dtA_g,
        float* __restrict__ y_g, ushort* __restrict__ cstate, float* __restrict__ css_g){
    int bid = blockIdx.x;                  // ((b*64+c)*16+h)
    int h = bid & 15, c = (bid >> 4) & 63, b = bid >> 10;
    int tid = threadIdx.x;
    int lane = tid & 63, wave = tid >> 6;
    int r0 = b*SEQ + c*BLOCKL;

    __shared__ __align__(16) char region0[18432];   // Cs72+Bs72, reused as Mf[64][65]
    __shared__ __align__(16) ushort XdT [64*72];    // Xd^T  [p][l]
    __shared__ __align__(16) ushort WXdT[64*72];    // (w·Xd)^T [p][l]
    __shared__ __align__(16) ushort BT  [64*72];    // B^T   [n][l]
    __shared__ float csh[64], dtsh[64], wsh[64];
    ushort* Cs = (ushort*)region0;            // [64][72]
    ushort* Bs = (ushort*)(region0 + 9216);   // [64][72]
    float*  Mf = (float*)region0;             // [64][65]

    int l  = tid >> 2;
    int c0 = (tid & 3) * 16;

    // coalesced row loads into registers
    f32x4 xr[4], br[4], cr[4];
    {
        const float* xp = X   + (size_t)(r0 + l)*DIM + h*HEADDIM + c0;
        const float* bp = Bin + (size_t)(r0 + l)*DIM + h*DSTATE  + c0;
        const float* cp = Cin + (size_t)(r0 + l)*DIM + h*DSTATE  + c0;
        #pragma unroll
        for (int q = 0; q < 4; ++q){
            xr[q] = *(const f32x4*)(xp + q*4);
            br[q] = *(const f32x4*)(bp + q*4);
            cr[q] = *(const f32x4*)(cp + q*4);
        }
    }
    if (tid < 64){
        dtsh[tid] = dt_g[(size_t)(r0 + tid)*HEADS + h];
        float a = dtA_g[(size_t)(r0 + tid)*HEADS + h];
        #pragma unroll
        for (int off = 1; off < 64; off <<= 1){
            float v = __shfl_up(a, off, 64);
            if (tid >= off) a += v;
        }
        csh[tid] = a;
        css_g[(size_t)bid*64 + tid] = a;
        float cs63 = __shfl(a, 63, 64);
        wsh[tid] = __expf(cs63 - a);
    }
    // row-major staging of C, B (independent of the scan)
    ushort tc[16], tb[16];
    #pragma unroll
    for (int q = 0; q < 4; ++q)
        #pragma unroll
        for (int j = 0; j < 4; ++j){
            tc[q*4+j] = f2b(cr[q][j]);
            tb[q*4+j] = f2b(br[q][j]);
        }
    *(uint4*)&Cs[l*72 + c0]     = *(uint4*)&tc[0];
    *(uint4*)&Cs[l*72 + c0 + 8] = *(uint4*)&tc[8];
    *(uint4*)&Bs[l*72 + c0]     = *(uint4*)&tb[0];
    *(uint4*)&Bs[l*72 + c0 + 8] = *(uint4*)&tb[8];
    __syncthreads();     // csh/dtsh/wsh + Cs/Bs ready

    // transposed tiles via u16 scatter from registers
    {
        float dl = dtsh[l], wl = wsh[l];
        #pragma unroll
        for (int q = 0; q < 4; ++q)
            #pragma unroll
            for (int j = 0; j < 4; ++j){
                int p = c0 + q*4 + j;
                float xv = xr[q][j] * dl;
                XdT [p*72 + l] = f2b(xv);
                WXdT[p*72 + l] = f2b(xv * wl);
                BT  [p*72 + l] = tb[q*4+j];
            }
    }
    __syncthreads();

    int cl15  = lane & 15;
    int g     = lane >> 4;
    int arow  = wave*16 + cl15;
    int kof   = g * 8;
    int rbase = wave*16 + g*4;

    // ---- G = C·B^T ---------------------------------------------------------
    f32x4 gacc[4];
    #pragma unroll
    for (int j = 0; j < 4; ++j) gacc[j] = (f32x4){0.f,0.f,0.f,0.f};
    #pragma unroll
    for (int k = 0; k < 2; ++k){
        bf16x8 a = *(const bf16x8*)&Cs[arow*72 + k*32 + kof];
        #pragma unroll
        for (int j = 0; j < 4; ++j){
            bf16x8 bb = *(const bf16x8*)&Bs[(16*j + cl15)*72 + k*32 + kof];
            gacc[j] = __builtin_amdgcn_mfma_f32_16x16x32_bf16(a, bb, gacc[j], 0, 0, 0);
        }
    }
    __syncthreads();   // region0 -> Mf

    // ---- M = tril(G * exp(cs[l]-cs[s])) ------------------------------------
    #pragma unroll
    for (int j = 0; j < 4; ++j){
        #pragma unroll
        for (int r = 0; r < 4; ++r){
            int row = rbase + r, col = 16*j + cl15;
            float m = 0.f;
            if (col <= row) m = gacc[j][r] * __expf(csh[row] - csh[col]);
            Mf[row*65 + col] = m;
        }
    }
    __syncthreads();

    // ---- Y_diag = M·Xd  (A: M bf16-converted; B: XdT rows) ------------------
    f32x4 y[4];
    #pragma unroll
    for (int j = 0; j < 4; ++j) y[j] = (f32x4){0.f,0.f,0.f,0.f};
    #pragma unroll
    for (int k = 0; k < 2; ++k){
        bf16x8 am;
        #pragma unroll
        for (int i = 0; i < 8; ++i)
            am[i] = (short)f2b(Mf[arow*65 + k*32 + kof + i]);
        #pragma unroll
        for (int j = 0; j < 4; ++j){
            bf16x8 bx = *(const bf16x8*)&XdT[(16*j + cl15)*72 + k*32 + kof];
            y[j] = __builtin_amdgcn_mfma_f32_16x16x32_bf16(am, bx, y[j], 0, 0, 0);
        }
    }
    #pragma unroll
    for (int j = 0; j < 4; ++j)
        #pragma unroll
        for (int r = 0; r < 4; ++r)
            y_g[(size_t)(r0 + rbase + r)*DIM + h*HEADDIM + 16*j + cl15] = y[j][r];

    // ---- chunk_state[p][n] = sum_l WXdT[p][l] * BT[n][l] --------------------
    f32x4 st[4];
    #pragma unroll
    for (int j = 0; j < 4; ++j) st[j] = (f32x4){0.f,0.f,0.f,0.f};
    #pragma unroll
    for (int k = 0; k < 2; ++k){
        bf16x8 aw = *(const bf16x8*)&WXdT[arow*72 + k*32 + kof];
        #pragma unroll
        for (int j = 0; j < 4; ++j){
            bf16x8 bb = *(const bf16x8*)&BT[(16*j + cl15)*72 + k*32 + kof];
            st[j] = __builtin_amdgcn_mfma_f32_16x16x32_bf16(aw, bb, st[j], 0, 0, 0);
        }
    }
    #pragma unroll
    for (int j = 0; j < 4; ++j)
        #pragma unroll
        for (int r = 0; r < 4; ++r){
            __half hv = __float2half(st[j][r]);
            cstate[(size_t)bid*4096 + (size_t)(rbase + r)*64 + 16*j + cl15] = *(ushort*)&hv;
        }
}

// ---------------------------------------------------------------------------
// K3: inter-chunk scan (f16 states, f32 running sum), emit final_state f32
__global__ __launch_bounds__(256) void k_scan(ushort* __restrict__ cstate,
        const float* __restrict__ css_g, float* __restrict__ fs_out){
    int bid = blockIdx.x;                  // b(2) * h(16) * tile(8)
    int tile = bid & 7, hh = (bid >> 3) & 15, b = bid >> 7;
    int pn = tile*512 + threadIdx.x*2;
    float P0 = 0.f, P1 = 0.f;
    for (int c = 0; c < NCHUNK; ++c){
        size_t base = (size_t)((b*NCHUNK + c)*HEADS + hh);
        float e = __expf(css_g[base*64 + 63]);
        __half2 cur = *(const __half2*)&cstate[base*4096 + pn];
        *( __half2*)&cstate[base*4096 + pn] = __floats2half2_rn(P0, P1);
        float2 cf = __half22float2(cur);
        P0 = e*P0 + cf.x;
        P1 = e*P1 + cf.y;
    }
    *(float2*)&fs_out[(size_t)(b*HEADS + hh)*4096 + pn] = make_float2(P0, P1);
}

// ---------------------------------------------------------------------------
// K4: fused Y_off + add Y_diag + LayerNorm -> yn bf16.  8 rows per block.
__global__ __launch_bounds__(256) void k_yln(const float* __restrict__ Cin,
        const ushort* __restrict__ cstate, const float* __restrict__ css_g,
        const float* __restrict__ y_g, const float* __restrict__ scale,
        const float* __restrict__ bias, __hip_bfloat16* __restrict__ yn){
    int blk = blockIdx.x;                 // b(2) * ch(64) * lg(8)
    int lg = blk & 7, ch = (blk >> 3) & 63, b = blk >> 9;
    int tid = threadIdx.x;
    int lane = tid & 63, wave = tid >> 6;
    int h = tid >> 4;
    int r0 = b*SEQ + ch*BLOCKL + lg*8;

    __shared__ uint Crow[8][16*33 + 1];   // f16 pairs, padded stride 33
    __shared__ float eh2[8][16];
    __shared__ float r1s[8][5], r2s[8][5];

    #pragma unroll
    for (int lr = 0; lr < 8; ++lr){
        f32x4 cv = *(const f32x4*)(Cin + (size_t)(r0 + lr)*DIM + tid*4);
        __half2 p0 = __floats2half2_rn(cv.x, cv.y);
        __half2 p1 = __floats2half2_rn(cv.z, cv.w);
        Crow[lr][h*33 + (tid & 15)*2]     = *(uint*)&p0;
        Crow[lr][h*33 + (tid & 15)*2 + 1] = *(uint*)&p1;
    }
    if (tid < 128){
        int lr = tid >> 4, hq = tid & 15;
        eh2[lr][hq] = __expf(css_g[(size_t)(((b*64 + ch)*16 + hq))*64 + lg*8 + lr]);
    }
    float yy[8][4];
    #pragma unroll
    for (int lr = 0; lr < 8; ++lr){
        f32x4 yv = *(const f32x4*)(y_g + (size_t)(r0 + lr)*DIM + tid*4);
        yy[lr][0] = yv.x; yy[lr][1] = yv.y; yy[lr][2] = yv.z; yy[lr][3] = yv.w;
    }
    __syncthreads();

    const ushort* Sb = cstate + (size_t)(((b*64 + ch)*16 + h))*4096;
    int p00 = (tid & 15)*4;
    #pragma unroll
    for (int j = 0; j < 4; ++j){
        const uint4* Sp = (const uint4*)(Sb + (size_t)(p00 + j)*64);
        uint4 sv[8];
        #pragma unroll
        for (int q = 0; q < 8; ++q) sv[q] = Sp[q];
        #pragma unroll
        for (int lr = 0; lr < 8; ++lr){
            float acc = 0.f;
            #pragma unroll
            for (int q = 0; q < 8; ++q){
                acc = fdot2u(sv[q].x, Crow[lr][h*33 + q*4 + 0], acc);
                acc = fdot2u(sv[q].y, Crow[lr][h*33 + q*4 + 1], acc);
                acc = fdot2u(sv[q].z, Crow[lr][h*33 + q*4 + 2], acc);
                acc = fdot2u(sv[q].w, Crow[lr][h*33 + q*4 + 3], acc);
            }
            yy[lr][j] += eh2[lr][h] * acc;
        }
    }

    float mu[8], rs[8];
    #pragma unroll
    for (int lr = 0; lr < 8; ++lr){
        float s1 = yy[lr][0] + yy[lr][1] + yy[lr][2] + yy[lr][3];
        float s2 = yy[lr][0]*yy[lr][0] + yy[lr][1]*yy[lr][1]
                 + yy[lr][2]*yy[lr][2] + yy[lr][3]*yy[lr][3];
        #pragma unroll
        for (int m = 32; m > 0; m >>= 1){
            s1 += __shfl_xor(s1, m, 64);
            s2 += __shfl_xor(s2, m, 64);
        }
        if (lane == 0){ r1s[lr][wave] = s1; r2s[lr][wave] = s2; }
    }
    __syncthreads();
    #pragma unroll
    for (int lr = 0; lr < 8; ++lr){
        float S1 = r1s[lr][0] + r1s[lr][1] + r1s[lr][2] + r1s[lr][3];
        float S2 = r2s[lr][0] + r2s[lr][1] + r2s[lr][2] + r2s[lr][3];
        float m_ = S1 * (1.f/DIM);
        float v_ = S2 * (1.f/DIM) - m_*m_;
        mu[lr] = m_;
        rs[lr] = rsqrtf(v_ + 1e-6f);
    }
    f32x4 sc = *(const f32x4*)(scale + tid*4);
    f32x4 bi = *(const f32x4*)(bias + tid*4);
    #pragma unroll
    for (int lr = 0; lr < 8; ++lr){
        union { __hip_bfloat16 hh[4]; short4 s4; } u;
        #pragma unroll
        for (int j = 0; j < 4; ++j)
            u.hh[j] = __float2bfloat16((yy[lr][j] - mu[lr])*rs[lr]*sc[j] + bi[j]);
        *(short4*)((short*)yn + (size_t)(r0 + lr)*DIM + tid*4) = u.s4;
    }
}

// ---------------------------------------------------------------------------
// K5b: Wt[n][k] = bf16(W_out[k][n])
__global__ __launch_bounds__(256) void k_wt(const float* __restrict__ W,
        __hip_bfloat16* __restrict__ Wt){
    __shared__ float t[64][65];
    int kt = blockIdx.x >> 4, nt = blockIdx.x & 15;
    int tid = threadIdx.x;
    int lr = tid >> 4, lc4 = (tid & 15) * 4;
    #pragma unroll
    for (int q = 0; q < 4; ++q){
        int k = lr + q*16;
        *(f32x4*)&t[k][lc4] = *(const f32x4*)(W + (size_t)(kt*64 + k)*DIM + nt*64 + lc4);
    }
    __syncthreads();
    #pragma unroll
    for (int q = 0; q < 4; ++q){
        int n = lr + q*16;
        union { __hip_bfloat16 h[4]; short4 s4; } u;
        #pragma unroll
        for (int j = 0; j < 4; ++j) u.h[j] = __float2bfloat16(t[lc4+j][n]);
        *(short4*)((short*)Wt + (size_t)(nt*64 + n)*DIM + kt*64 + lc4) = u.s4;
    }
}

// ---------------------------------------------------------------------------
// K6: Out = yn @ Wt^T (bf16 MFMA, f32 accum), global_load_lds staging
__global__ __launch_bounds__(256) void k_gemm(const __hip_bfloat16* __restrict__ A,
        const __hip_bfloat16* __restrict__ Bt, float* __restrict__ Out){
    __shared__ __align__(16) ushort As[128*32];
    __shared__ __align__(16) ushort Bsh[128*32];
    int bid = blockIdx.x;
    int bn = bid & 7, bm = bid >> 3;
    int tid = threadIdx.x;
    int lane = tid & 63, wave = tid >> 6;
    int wr = wave >> 1, wc = wave & 1;
    f32x4 acc[4][4];
    #pragma unroll
    for (int i = 0; i < 4; ++i)
        #pragma unroll
        for (int j = 0; j < 4; ++j)
            acc[i][j] = (f32x4){0.f, 0.f, 0.f, 0.f};
    const ushort* Ag = (const ushort*)A  + (size_t)bm*128*1024;
    const ushort* Bg = (const ushort*)Bt + (size_t)bn*128*1024;
    int row0 = tid >> 2;
    int col0 = (tid & 3) * 8;
    for (int k0 = 0; k0 < 1024; k0 += 32){
        const ushort* sA = Ag + (size_t)row0*1024 + k0 + col0;
        const ushort* sB = Bg + (size_t)row0*1024 + k0 + col0;
        gload16(sA,           &As[row0*32 + col0]);
        gload16(sA + 64*1024, &As[(row0+64)*32 + col0]);
        gload16(sB,           &Bsh[row0*32 + col0]);
        gload16(sB + 64*1024, &Bsh[(row0+64)*32 + col0]);
        __syncthreads();
        bf16x8 af[4], bfr[4];
        #pragma unroll
        for (int i = 0; i < 4; ++i){
            int arow = wr*64 + i*16 + (lane & 15);
            af[i] = *(const bf16x8*)&As[arow*32 + ((lane >> 4) << 3)];
        }
        #pragma unroll
        for (int j = 0; j < 4; ++j){
            int brow = wc*64 + j*16 + (lane & 15);
            bfr[j] = *(const bf16x8*)&Bsh[brow*32 + ((lane >> 4) << 3)];
        }
        #pragma unroll
        for (int i = 0; i < 4; ++i)
            #pragma unroll
            for (int j = 0; j < 4; ++j)
                acc[i][j] = __builtin_amdgcn_mfma_f32_16x16x32_bf16(af[i], bfr[j], acc[i][j], 0, 0, 0);
        __syncthreads();
    }
    #pragma unroll
    for (int i = 0; i < 4; ++i){
        int m0 = bm*128 + wr*64 + i*16 + ((lane >> 4) << 2);
        #pragma unroll
        for (int j = 0; j < 4; ++j){
            int n = bn*128 + wc*64 + j*16 + (lane & 15);
            #pragma unroll
            for (int reg = 0; reg < 4; ++reg)
                Out[(size_t)(m0 + reg)*1024 + n] = acc[i][j][reg];
        }
    }
}

// ---------------------------------------------------------------------------
extern "C" void kernel_launch(void* const* d_in, const int* in_sizes, int n_in,
                              void* d_out, int out_size, void* d_ws, size_t ws_size,
                              hipStream_t stream){
    const float* X    = (const float*)d_in[0];
    const float* Bin  = (const float*)d_in[1];
    const float* Cin  = (const float*)d_in[2];
    const float* Wdt  = (const float*)d_in[3];
    const float* dtb  = (const float*)d_in[4];
    const float* alog = (const float*)d_in[5];
    const float* Wout = (const float*)d_in[6];
    const float* lns  = (const float*)d_in[7];
    const float* lnb  = (const float*)d_in[8];

    float* out = (float*)d_out;
    float* y_g = out;                       // reuse out region as y buffer
    float* fs_out = out + (size_t)ROWS*DIM;

    float* dt_g   = (float*)d_ws;                        // 131072 f32
    float* dtA_g  = dt_g  + 131072;                      // 131072 f32
    float* css_g  = dtA_g + 131072;                      // 131072 f32
    ushort* cstate = (ushort*)(css_g + 131072);          // 8388608 f16
    __hip_bfloat16* yn = (__hip_bfloat16*)(cstate + 8388608); // 8388608 bf16
    __hip_bfloat16* Wt = yn + (size_t)ROWS*DIM;          // 1048576 bf16

    k_dt   <<<ROWS,               256, 0, stream>>>(X, Wdt, dtb, alog, dt_g, dtA_g);
    k_chunk<<<BATCH*NCHUNK*HEADS, 256, 0, stream>>>(X, Bin, Cin, dt_g, dtA_g, y_g, cstate, css_g);
    k_scan <<<BATCH*HEADS*8,      256, 0, stream>>>(cstate, css_g, fs_out);
    k_yln  <<<BATCH*NCHUNK*8,     256, 0, stream>>>(Cin, cstate, css_g, y_g, lns, lnb, yn);
    k_wt   <<<256,                256, 0, stream>>>(Wout, Wt);
    k_gemm <<<512,                256, 0, stream>>>(yn, Wt, out);
}

// Round 5
// 131.799 us; speedup vs baseline: 1.2738x; 1.2738x over previous
//
#include <hip/hip_runtime.h>
#include <hip/hip_bf16.h>
#include <hip/hip_fp16.h>
#include <math.h>

#define BATCH   2
#define SEQ     4096
#define DIM     1024
#define HEADS   16
#define DSTATE  64
#define HEADDIM 64
#define BLOCKL  64
#define NCHUNK  64
#define ROWS    (BATCH*SEQ)

typedef __attribute__((ext_vector_type(4))) float f32x4;
typedef __attribute__((ext_vector_type(8))) short bf16x8;
typedef __attribute__((ext_vector_type(8))) _Float16 f16x8;

static __device__ __forceinline__ float softplus_f(float x){
    return (x > 20.f) ? x : log1pf(__expf(x));
}
static __device__ __forceinline__ ushort f2b(float f){
    __hip_bfloat16 h = __float2bfloat16(f);
    return *reinterpret_cast<ushort*>(&h);
}
static __device__ __forceinline__ void gload16(const void* g, void* l){
    __builtin_amdgcn_global_load_lds((const __attribute__((address_space(1))) unsigned int*)g,
                                     (__attribute__((address_space(3))) unsigned int*)l, 16, 0, 0);
}

// ---------------------------------------------------------------------------
// K1: dt = softplus(X@W_dt + bias); dtA = -exp(a_log)*dt
__global__ __launch_bounds__(256) void k_dt(const float* __restrict__ X,
        const float* __restrict__ Wdt, const float* __restrict__ dtb,
        const float* __restrict__ alog,
        float* __restrict__ dt_g, float* __restrict__ dtA_g){
    int r = blockIdx.x;
    int s = r & (SEQ-1);
    int tid = threadIdx.x;
    __shared__ float xrow[DIM];
    __shared__ float red[16][17];
    *(f32x4*)(xrow + tid*4) = *(const f32x4*)(X + (size_t)r*DIM + tid*4);
    __syncthreads();
    int part = tid >> 4, h = tid & 15;
    int d0 = part * 64;
    float acc = 0.f;
    #pragma unroll 8
    for (int i = 0; i < 64; ++i)
        acc += xrow[d0 + i] * Wdt[(size_t)(d0 + i)*HEADS + h];
    red[part][h] = acc;
    __syncthreads();
    if (tid < 16){
        float sum = 0.f;
        #pragma unroll
        for (int p = 0; p < 16; ++p) sum += red[p][tid];
        sum += dtb[(size_t)s*HEADS + tid];
        float dtv = softplus_f(sum);
        dt_g[(size_t)r*HEADS + tid]  = dtv;
        dtA_g[(size_t)r*HEADS + tid] = -__expf(alog[tid]) * dtv;
    }
}

// ---------------------------------------------------------------------------
// K2 (MFMA): G=C·B^T -> M ; Y_diag=M·Xd ; chunk_state = (w·Xd)^T·B
__global__ __launch_bounds__(256) void k_chunk(const float* __restrict__ X,
        const float* __restrict__ Bin, const float* __restrict__ Cin,
        const float* __restrict__ dt_g, const float* __restrict__ dtA_g,
        float* __restrict__ y_g, ushort* __restrict__ cstate, float* __restrict__ css_g){
    int bid = blockIdx.x;                  // ((b*64+c)*16+h)
    int h = bid & 15, c = (bid >> 4) & 63, b = bid >> 10;
    int tid = threadIdx.x;
    int lane = tid & 63, wave = tid >> 6;
    int r0 = b*SEQ + c*BLOCKL;

    __shared__ __align__(16) char region0[18432];   // Cs72+Bs72, reused as Mf[64][65]
    __shared__ __align__(16) ushort XdT [64*72];    // Xd^T  [p][l]
    __shared__ __align__(16) ushort WXdT[64*72];    // (w·Xd)^T [p][l]
    __shared__ __align__(16) ushort BT  [64*72];    // B^T   [n][l]
    __shared__ float csh[64], dtsh[64], wsh[64];
    ushort* Cs = (ushort*)region0;            // [64][72]
    ushort* Bs = (ushort*)(region0 + 9216);   // [64][72]
    float*  Mf = (float*)region0;             // [64][65]

    int l  = tid >> 2;
    int c0 = (tid & 3) * 16;

    f32x4 xr[4], br[4], cr[4];
    {
        const float* xp = X   + (size_t)(r0 + l)*DIM + h*HEADDIM + c0;
        const float* bp = Bin + (size_t)(r0 + l)*DIM + h*DSTATE  + c0;
        const float* cp = Cin + (size_t)(r0 + l)*DIM + h*DSTATE  + c0;
        #pragma unroll
        for (int q = 0; q < 4; ++q){
            xr[q] = *(const f32x4*)(xp + q*4);
            br[q] = *(const f32x4*)(bp + q*4);
            cr[q] = *(const f32x4*)(cp + q*4);
        }
    }
    if (tid < 64){
        dtsh[tid] = dt_g[(size_t)(r0 + tid)*HEADS + h];
        float a = dtA_g[(size_t)(r0 + tid)*HEADS + h];
        #pragma unroll
        for (int off = 1; off < 64; off <<= 1){
            float v = __shfl_up(a, off, 64);
            if (tid >= off) a += v;
        }
        csh[tid] = a;
        css_g[(size_t)bid*64 + tid] = a;
        float cs63 = __shfl(a, 63, 64);
        wsh[tid] = __expf(cs63 - a);
    }
    ushort tc[16], tb[16];
    #pragma unroll
    for (int q = 0; q < 4; ++q)
        #pragma unroll
        for (int j = 0; j < 4; ++j){
            tc[q*4+j] = f2b(cr[q][j]);
            tb[q*4+j] = f2b(br[q][j]);
        }
    *(uint4*)&Cs[l*72 + c0]     = *(uint4*)&tc[0];
    *(uint4*)&Cs[l*72 + c0 + 8] = *(uint4*)&tc[8];
    *(uint4*)&Bs[l*72 + c0]     = *(uint4*)&tb[0];
    *(uint4*)&Bs[l*72 + c0 + 8] = *(uint4*)&tb[8];
    __syncthreads();

    {
        float dl = dtsh[l], wl = wsh[l];
        #pragma unroll
        for (int q = 0; q < 4; ++q)
            #pragma unroll
            for (int j = 0; j < 4; ++j){
                int p = c0 + q*4 + j;
                float xv = xr[q][j] * dl;
                XdT [p*72 + l] = f2b(xv);
                WXdT[p*72 + l] = f2b(xv * wl);
                BT  [p*72 + l] = tb[q*4+j];
            }
    }
    __syncthreads();

    int cl15  = lane & 15;
    int g     = lane >> 4;
    int arow  = wave*16 + cl15;
    int kof   = g * 8;
    int rbase = wave*16 + g*4;

    f32x4 gacc[4];
    #pragma unroll
    for (int j = 0; j < 4; ++j) gacc[j] = (f32x4){0.f,0.f,0.f,0.f};
    #pragma unroll
    for (int k = 0; k < 2; ++k){
        bf16x8 a = *(const bf16x8*)&Cs[arow*72 + k*32 + kof];
        #pragma unroll
        for (int j = 0; j < 4; ++j){
            bf16x8 bb = *(const bf16x8*)&Bs[(16*j + cl15)*72 + k*32 + kof];
            gacc[j] = __builtin_amdgcn_mfma_f32_16x16x32_bf16(a, bb, gacc[j], 0, 0, 0);
        }
    }
    __syncthreads();

    #pragma unroll
    for (int j = 0; j < 4; ++j){
        #pragma unroll
        for (int r = 0; r < 4; ++r){
            int row = rbase + r, col = 16*j + cl15;
            float m = 0.f;
            if (col <= row) m = gacc[j][r] * __expf(csh[row] - csh[col]);
            Mf[row*65 + col] = m;
        }
    }
    __syncthreads();

    f32x4 y[4];
    #pragma unroll
    for (int j = 0; j < 4; ++j) y[j] = (f32x4){0.f,0.f,0.f,0.f};
    #pragma unroll
    for (int k = 0; k < 2; ++k){
        bf16x8 am;
        #pragma unroll
        for (int i = 0; i < 8; ++i)
            am[i] = (short)f2b(Mf[arow*65 + k*32 + kof + i]);
        #pragma unroll
        for (int j = 0; j < 4; ++j){
            bf16x8 bx = *(const bf16x8*)&XdT[(16*j + cl15)*72 + k*32 + kof];
            y[j] = __builtin_amdgcn_mfma_f32_16x16x32_bf16(am, bx, y[j], 0, 0, 0);
        }
    }
    #pragma unroll
    for (int j = 0; j < 4; ++j)
        #pragma unroll
        for (int r = 0; r < 4; ++r)
            y_g[(size_t)(r0 + rbase + r)*DIM + h*HEADDIM + 16*j + cl15] = y[j][r];

    f32x4 st[4];
    #pragma unroll
    for (int j = 0; j < 4; ++j) st[j] = (f32x4){0.f,0.f,0.f,0.f};
    #pragma unroll
    for (int k = 0; k < 2; ++k){
        bf16x8 aw = *(const bf16x8*)&WXdT[arow*72 + k*32 + kof];
        #pragma unroll
        for (int j = 0; j < 4; ++j){
            bf16x8 bb = *(const bf16x8*)&BT[(16*j + cl15)*72 + k*32 + kof];
            st[j] = __builtin_amdgcn_mfma_f32_16x16x32_bf16(aw, bb, st[j], 0, 0, 0);
        }
    }
    #pragma unroll
    for (int j = 0; j < 4; ++j)
        #pragma unroll
        for (int r = 0; r < 4; ++r){
            __half hv = __float2half(st[j][r]);
            cstate[(size_t)bid*4096 + (size_t)(rbase + r)*64 + 16*j + cl15] = *(ushort*)&hv;
        }
}

// ---------------------------------------------------------------------------
// K3: inter-chunk scan (f16 states, f32 running sum), emit final_state f32
__global__ __launch_bounds__(256) void k_scan(ushort* __restrict__ cstate,
        const float* __restrict__ css_g, float* __restrict__ fs_out){
    int bid = blockIdx.x;                  // b(2) * h(16) * tile(8)
    int tile = bid & 7, hh = (bid >> 3) & 15, b = bid >> 7;
    int pn = tile*512 + threadIdx.x*2;
    float P0 = 0.f, P1 = 0.f;
    for (int c = 0; c < NCHUNK; ++c){
        size_t base = (size_t)((b*NCHUNK + c)*HEADS + hh);
        float e = __expf(css_g[base*64 + 63]);
        __half2 cur = *(const __half2*)&cstate[base*4096 + pn];
        *( __half2*)&cstate[base*4096 + pn] = __floats2half2_rn(P0, P1);
        float2 cf = __half22float2(cur);
        P0 = e*P0 + cf.x;
        P1 = e*P1 + cf.y;
    }
    *(float2*)&fs_out[(size_t)(b*HEADS + hh)*4096 + pn] = make_float2(P0, P1);
}

// ---------------------------------------------------------------------------
// K4 (f16 MFMA): Y_off[l][p] = exp(cs[l]) * sum_n C[l][n]*S[p][n];  y += Y_off
__global__ __launch_bounds__(256) void k_yoff(const float* __restrict__ Cin,
        const ushort* __restrict__ cstate, const float* __restrict__ css_g,
        float* __restrict__ y_g){
    int bid = blockIdx.x;
    int h = bid & 15, c = (bid >> 4) & 63, b = bid >> 10;
    int tid = threadIdx.x;
    int lane = tid & 63, wave = tid >> 6;
    int r0 = b*SEQ + c*BLOCKL;
    __shared__ __align__(16) ushort Cs[64*72];   // C rows as f16 [l][n]
    __shared__ __align__(16) ushort Ss[64*72];   // S rows f16 [p][n]
    __shared__ float cse[64];
    {
        int l  = tid >> 2;
        int c0 = (tid & 3) * 16;
        const float* cp = Cin + (size_t)(r0 + l)*DIM + h*DSTATE + c0;
        ushort tc[16];
        #pragma unroll
        for (int q = 0; q < 4; ++q){
            f32x4 vc = *(const f32x4*)(cp + q*4);
            #pragma unroll
            for (int j = 0; j < 4; ++j){
                __half hv = __float2half(vc[j]);
                tc[q*4+j] = *(ushort*)&hv;
            }
        }
        *(uint4*)&Cs[l*72 + c0]     = *(uint4*)&tc[0];
        *(uint4*)&Cs[l*72 + c0 + 8] = *(uint4*)&tc[8];
        // S: already f16, coalesced row loads
        const ushort* sp = cstate + (size_t)bid*4096 + (size_t)l*64 + c0;
        *(uint4*)&Ss[l*72 + c0]     = *(const uint4*)sp;
        *(uint4*)&Ss[l*72 + c0 + 8] = *(const uint4*)(sp + 8);
    }
    if (tid < 64) cse[tid] = __expf(css_g[(size_t)bid*64 + tid]);
    __syncthreads();

    int cl15 = lane & 15;
    int g    = lane >> 4;
    int arow = wave*16 + cl15;
    int kof  = g * 8;
    f32x4 acc[4];
    #pragma unroll
    for (int j = 0; j < 4; ++j) acc[j] = (f32x4){0.f,0.f,0.f,0.f};
    #pragma unroll
    for (int k = 0; k < 2; ++k){
        f16x8 a = *(const f16x8*)&Cs[arow*72 + k*32 + kof];
        #pragma unroll
        for (int j = 0; j < 4; ++j){
            f16x8 bb = *(const f16x8*)&Ss[(16*j + cl15)*72 + k*32 + kof];
            acc[j] = __builtin_amdgcn_mfma_f32_16x16x32_f16(a, bb, acc[j], 0, 0, 0);
        }
    }
    int rbase = wave*16 + g*4;
    #pragma unroll
    for (int j = 0; j < 4; ++j)
        #pragma unroll
        for (int r = 0; r < 4; ++r){
            float e = cse[rbase + r];
            float* yp = y_g + (size_t)(r0 + rbase + r)*DIM + h*HEADDIM + 16*j + cl15;
            *yp += e * acc[j][r];
        }
}

// ---------------------------------------------------------------------------
// K5: LayerNorm over dim, write bf16 yn
__global__ __launch_bounds__(256) void k_ln(const float* __restrict__ y_g,
        const float* __restrict__ scale, const float* __restrict__ bias,
        __hip_bfloat16* __restrict__ yn){
    int r = blockIdx.x, tid = threadIdx.x;
    const float* yp = y_g + (size_t)r*DIM;
    f32x4 v = *(const f32x4*)(yp + tid*4);
    float s1 = v.x + v.y + v.z + v.w;
    float s2 = v.x*v.x + v.y*v.y + v.z*v.z + v.w*v.w;
    #pragma unroll
    for (int m = 32; m > 0; m >>= 1){
        s1 += __shfl_xor(s1, m, 64);
        s2 += __shfl_xor(s2, m, 64);
    }
    __shared__ float w1[4], w2[4];
    int wv = tid >> 6;
    if ((tid & 63) == 0){ w1[wv] = s1; w2[wv] = s2; }
    __syncthreads();
    float S1 = w1[0]+w1[1]+w1[2]+w1[3];
    float S2 = w2[0]+w2[1]+w2[2]+w2[3];
    float mu  = S1 * (1.f/DIM);
    float var = S2 * (1.f/DIM) - mu*mu;
    float rstd = rsqrtf(var + 1e-6f);
    int d = tid*4;
    f32x4 sc = *(const f32x4*)(scale + d);
    f32x4 bi = *(const f32x4*)(bias + d);
    union { __hip_bfloat16 h[4]; short4 s4; } u;
    u.h[0] = __float2bfloat16((v.x - mu)*rstd*sc.x + bi.x);
    u.h[1] = __float2bfloat16((v.y - mu)*rstd*sc.y + bi.y);
    u.h[2] = __float2bfloat16((v.z - mu)*rstd*sc.z + bi.z);
    u.h[3] = __float2bfloat16((v.w - mu)*rstd*sc.w + bi.w);
    *(short4*)((short*)yn + (size_t)r*DIM + d) = u.s4;
}

// ---------------------------------------------------------------------------
// K5b: Wt[n][k] = bf16(W_out[k][n])
__global__ __launch_bounds__(256) void k_wt(const float* __restrict__ W,
        __hip_bfloat16* __restrict__ Wt){
    __shared__ float t[64][65];
    int kt = blockIdx.x >> 4, nt = blockIdx.x & 15;
    int tid = threadIdx.x;
    int lr = tid >> 4, lc4 = (tid & 15) * 4;
    #pragma unroll
    for (int q = 0; q < 4; ++q){
        int k = lr + q*16;
        *(f32x4*)&t[k][lc4] = *(const f32x4*)(W + (size_t)(kt*64 + k)*DIM + nt*64 + lc4);
    }
    __syncthreads();
    #pragma unroll
    for (int q = 0; q < 4; ++q){
        int n = lr + q*16;
        union { __hip_bfloat16 h[4]; short4 s4; } u;
        #pragma unroll
        for (int j = 0; j < 4; ++j) u.h[j] = __float2bfloat16(t[lc4+j][n]);
        *(short4*)((short*)Wt + (size_t)(nt*64 + n)*DIM + kt*64 + lc4) = u.s4;
    }
}

// ---------------------------------------------------------------------------
// K6: Out = yn @ Wt^T (bf16 MFMA, f32 accum), global_load_lds staging
__global__ __launch_bounds__(256) void k_gemm(const __hip_bfloat16* __restrict__ A,
        const __hip_bfloat16* __restrict__ Bt, float* __restrict__ Out){
    __shared__ __align__(16) ushort As[128*32];
    __shared__ __align__(16) ushort Bsh[128*32];
    int bid = blockIdx.x;
    int bn = bid & 7, bm = bid >> 3;
    int tid = threadIdx.x;
    int lane = tid & 63, wave = tid >> 6;
    int wr = wave >> 1, wc = wave & 1;
    f32x4 acc[4][4];
    #pragma unroll
    for (int i = 0; i < 4; ++i)
        #pragma unroll
        for (int j = 0; j < 4; ++j)
            acc[i][j] = (f32x4){0.f, 0.f, 0.f, 0.f};
    const ushort* Ag = (const ushort*)A  + (size_t)bm*128*1024;
    const ushort* Bg = (const ushort*)Bt + (size_t)bn*128*1024;
    int row0 = tid >> 2;
    int col0 = (tid & 3) * 8;
    for (int k0 = 0; k0 < 1024; k0 += 32){
        const ushort* sA = Ag + (size_t)row0*1024 + k0 + col0;
        const ushort* sB = Bg + (size_t)row0*1024 + k0 + col0;
        gload16(sA,           &As[row0*32 + col0]);
        gload16(sA + 64*1024, &As[(row0+64)*32 + col0]);
        gload16(sB,           &Bsh[row0*32 + col0]);
        gload16(sB + 64*1024, &Bsh[(row0+64)*32 + col0]);
        __syncthreads();
        bf16x8 af[4], bfr[4];
        #pragma unroll
        for (int i = 0; i < 4; ++i){
            int arow = wr*64 + i*16 + (lane & 15);
            af[i] = *(const bf16x8*)&As[arow*32 + ((lane >> 4) << 3)];
        }
        #pragma unroll
        for (int j = 0; j < 4; ++j){
            int brow = wc*64 + j*16 + (lane & 15);
            bfr[j] = *(const bf16x8*)&Bsh[brow*32 + ((lane >> 4) << 3)];
        }
        #pragma unroll
        for (int i = 0; i < 4; ++i)
            #pragma unroll
            for (int j = 0; j < 4; ++j)
                acc[i][j] = __builtin_amdgcn_mfma_f32_16x16x32_bf16(af[i], bfr[j], acc[i][j], 0, 0, 0);
        __syncthreads();
    }
    #pragma unroll
    for (int i = 0; i < 4; ++i){
        int m0 = bm*128 + wr*64 + i*16 + ((lane >> 4) << 2);
        #pragma unroll
        for (int j = 0; j < 4; ++j){
            int n = bn*128 + wc*64 + j*16 + (lane & 15);
            #pragma unroll
            for (int reg = 0; reg < 4; ++reg)
                Out[(size_t)(m0 + reg)*1024 + n] = acc[i][j][reg];
        }
    }
}

// ---------------------------------------------------------------------------
extern "C" void kernel_launch(void* const* d_in, const int* in_sizes, int n_in,
                              void* d_out, int out_size, void* d_ws, size_t ws_size,
                              hipStream_t stream){
    const float* X    = (const float*)d_in[0];
    const float* Bin  = (const float*)d_in[1];
    const float* Cin  = (const float*)d_in[2];
    const float* Wdt  = (const float*)d_in[3];
    const float* dtb  = (const float*)d_in[4];
    const float* alog = (const float*)d_in[5];
    const float* Wout = (const float*)d_in[6];
    const float* lns  = (const float*)d_in[7];
    const float* lnb  = (const float*)d_in[8];

    float* out = (float*)d_out;
    float* y_g = out;                       // reuse out region as y buffer
    float* fs_out = out + (size_t)ROWS*DIM;

    float* dt_g   = (float*)d_ws;                        // 131072 f32
    float* dtA_g  = dt_g  + 131072;                      // 131072 f32
    float* css_g  = dtA_g + 131072;                      // 131072 f32
    ushort* cstate = (ushort*)(css_g + 131072);          // 8388608 f16
    __hip_bfloat16* yn = (__hip_bfloat16*)(cstate + 8388608); // 8388608 bf16
    __hip_bfloat16* Wt = yn + (size_t)ROWS*DIM;          // 1048576 bf16

    k_dt   <<<ROWS,               256, 0, stream>>>(X, Wdt, dtb, alog, dt_g, dtA_g);
    k_chunk<<<BATCH*NCHUNK*HEADS, 256, 0, stream>>>(X, Bin, Cin, dt_g, dtA_g, y_g, cstate, css_g);
    k_scan <<<BATCH*HEADS*8,      256, 0, stream>>>(cstate, css_g, fs_out);
    k_yoff <<<BATCH*NCHUNK*HEADS, 256, 0, stream>>>(Cin, cstate, css_g, y_g);
    k_ln   <<<ROWS,               256, 0, stream>>>(y_g, lns, lnb, yn);
    k_wt   <<<256,                256, 0, stream>>>(Wout, Wt);
    k_gemm <<<512,                256, 0, stream>>>(yn, Wt, out);
}

// Round 6
// 127.018 us; speedup vs baseline: 1.3217x; 1.0376x over previous
//
#include <hip/hip_runtime.h>
#include <hip/hip_bf16.h>
#include <hip/hip_fp16.h>
#include <math.h>

#define BATCH   2
#define SEQ     4096
#define DIM     1024
#define HEADS   16
#define DSTATE  64
#define HEADDIM 64
#define BLOCKL  64
#define NCHUNK  64
#define ROWS    (BATCH*SEQ)

typedef __attribute__((ext_vector_type(4))) float f32x4;
typedef __attribute__((ext_vector_type(8))) short bf16x8;
typedef __attribute__((ext_vector_type(8))) _Float16 f16x8;

static __device__ __forceinline__ float softplus_f(float x){
    return (x > 20.f) ? x : log1pf(__expf(x));
}
static __device__ __forceinline__ ushort f2b(float f){
    __hip_bfloat16 h = __float2bfloat16(f);
    return *reinterpret_cast<ushort*>(&h);
}
static __device__ __forceinline__ float b2f(ushort u){
    uint x = ((uint)u) << 16;
    return *reinterpret_cast<float*>(&x);
}
static __device__ __forceinline__ void gload16(const void* g, void* l){
    __builtin_amdgcn_global_load_lds((const __attribute__((address_space(1))) unsigned int*)g,
                                     (__attribute__((address_space(3))) unsigned int*)l, 16, 0, 0);
}

// ---------------------------------------------------------------------------
// K1: dt = softplus(X@W_dt + bias); dtA = -exp(a_log)*dt
__global__ __launch_bounds__(256) void k_dt(const float* __restrict__ X,
        const float* __restrict__ Wdt, const float* __restrict__ dtb,
        const float* __restrict__ alog,
        float* __restrict__ dt_g, float* __restrict__ dtA_g){
    int r = blockIdx.x;
    int s = r & (SEQ-1);
    int tid = threadIdx.x;
    __shared__ float xrow[DIM];
    __shared__ float red[16][17];
    *(f32x4*)(xrow + tid*4) = *(const f32x4*)(X + (size_t)r*DIM + tid*4);
    __syncthreads();
    int part = tid >> 4, h = tid & 15;
    int d0 = part * 64;
    float acc = 0.f;
    #pragma unroll 8
    for (int i = 0; i < 64; ++i)
        acc += xrow[d0 + i] * Wdt[(size_t)(d0 + i)*HEADS + h];
    red[part][h] = acc;
    __syncthreads();
    if (tid < 16){
        float sum = 0.f;
        #pragma unroll
        for (int p = 0; p < 16; ++p) sum += red[p][tid];
        sum += dtb[(size_t)s*HEADS + tid];
        float dtv = softplus_f(sum);
        dt_g[(size_t)r*HEADS + tid]  = dtv;
        dtA_g[(size_t)r*HEADS + tid] = -__expf(alog[tid]) * dtv;
    }
}

// ---------------------------------------------------------------------------
// K2 (MFMA): G=C·B^T -> M ; Y_diag=M·Xd (bf16 out) ; chunk_state = Xd^T·(w·B)
// LDS 36.75 KB -> 4 blocks/CU.
__global__ __launch_bounds__(256) void k_chunk(const float* __restrict__ X,
        const float* __restrict__ Bin, const float* __restrict__ Cin,
        const float* __restrict__ dt_g, const float* __restrict__ dtA_g,
        ushort* __restrict__ ybf, ushort* __restrict__ cstate, float* __restrict__ css_g){
    int bid = blockIdx.x;                  // ((b*64+c)*16+h)
    int h = bid & 15, c = (bid >> 4) & 63, b = bid >> 10;
    int tid = threadIdx.x;
    int lane = tid & 63, wave = tid >> 6;
    int r0 = b*SEQ + c*BLOCKL;

    __shared__ __align__(16) char region0[18432];   // Cs72+Bs72, reused as Mf[64][65]
    __shared__ __align__(16) ushort XdT[64*72];     // Xd^T  [p][l]
    __shared__ __align__(16) ushort WBT[64*72];     // (w·B)^T [n][l]
    __shared__ float csh[64], dtsh[64], wsh[64];
    ushort* Cs = (ushort*)region0;            // [64][72]
    ushort* Bs = (ushort*)(region0 + 9216);   // [64][72]
    float*  Mf = (float*)region0;             // [64][65]

    int l  = tid >> 2;
    int c0 = (tid & 3) * 16;

    f32x4 xr[4], br[4], cr[4];
    {
        const float* xp = X   + (size_t)(r0 + l)*DIM + h*HEADDIM + c0;
        const float* bp = Bin + (size_t)(r0 + l)*DIM + h*DSTATE  + c0;
        const float* cp = Cin + (size_t)(r0 + l)*DIM + h*DSTATE  + c0;
        #pragma unroll
        for (int q = 0; q < 4; ++q){
            xr[q] = *(const f32x4*)(xp + q*4);
            br[q] = *(const f32x4*)(bp + q*4);
            cr[q] = *(const f32x4*)(cp + q*4);
        }
    }
    if (tid < 64){
        dtsh[tid] = dt_g[(size_t)(r0 + tid)*HEADS + h];
        float a = dtA_g[(size_t)(r0 + tid)*HEADS + h];
        #pragma unroll
        for (int off = 1; off < 64; off <<= 1){
            float v = __shfl_up(a, off, 64);
            if (tid >= off) a += v;
        }
        csh[tid] = a;
        css_g[(size_t)bid*64 + tid] = a;
        float cs63 = __shfl(a, 63, 64);
        wsh[tid] = __expf(cs63 - a);
    }
    ushort tc[16], tb[16];
    #pragma unroll
    for (int q = 0; q < 4; ++q)
        #pragma unroll
        for (int j = 0; j < 4; ++j){
            tc[q*4+j] = f2b(cr[q][j]);
            tb[q*4+j] = f2b(br[q][j]);
        }
    *(uint4*)&Cs[l*72 + c0]     = *(uint4*)&tc[0];
    *(uint4*)&Cs[l*72 + c0 + 8] = *(uint4*)&tc[8];
    *(uint4*)&Bs[l*72 + c0]     = *(uint4*)&tb[0];
    *(uint4*)&Bs[l*72 + c0 + 8] = *(uint4*)&tb[8];
    __syncthreads();

    // transposed tiles via u16 scatter (32 writes/thread)
    {
        float dl = dtsh[l], wl = wsh[l];
        #pragma unroll
        for (int q = 0; q < 4; ++q)
            #pragma unroll
            for (int j = 0; j < 4; ++j){
                int p = c0 + q*4 + j;
                XdT[p*72 + l] = f2b(xr[q][j] * dl);
                WBT[p*72 + l] = f2b(br[q][j] * wl);
            }
    }
    __syncthreads();

    int cl15  = lane & 15;
    int g     = lane >> 4;
    int arow  = wave*16 + cl15;
    int kof   = g * 8;
    int rbase = wave*16 + g*4;

    // ---- G = C·B^T ---------------------------------------------------------
    f32x4 gacc[4];
    #pragma unroll
    for (int j = 0; j < 4; ++j) gacc[j] = (f32x4){0.f,0.f,0.f,0.f};
    #pragma unroll
    for (int k = 0; k < 2; ++k){
        bf16x8 a = *(const bf16x8*)&Cs[arow*72 + k*32 + kof];
        #pragma unroll
        for (int j = 0; j < 4; ++j){
            bf16x8 bb = *(const bf16x8*)&Bs[(16*j + cl15)*72 + k*32 + kof];
            gacc[j] = __builtin_amdgcn_mfma_f32_16x16x32_bf16(a, bb, gacc[j], 0, 0, 0);
        }
    }
    __syncthreads();

    // ---- M = tril(G * exp(cs[l]-cs[s])) ------------------------------------
    #pragma unroll
    for (int j = 0; j < 4; ++j){
        #pragma unroll
        for (int r = 0; r < 4; ++r){
            int row = rbase + r, col = 16*j + cl15;
            float m = 0.f;
            if (col <= row) m = gacc[j][r] * __expf(csh[row] - csh[col]);
            Mf[row*65 + col] = m;
        }
    }
    __syncthreads();

    // ---- Y_diag = M·Xd (bf16 store) ----------------------------------------
    f32x4 y[4];
    #pragma unroll
    for (int j = 0; j < 4; ++j) y[j] = (f32x4){0.f,0.f,0.f,0.f};
    #pragma unroll
    for (int k = 0; k < 2; ++k){
        bf16x8 am;
        #pragma unroll
        for (int i = 0; i < 8; ++i)
            am[i] = (short)f2b(Mf[arow*65 + k*32 + kof + i]);
        #pragma unroll
        for (int j = 0; j < 4; ++j){
            bf16x8 bx = *(const bf16x8*)&XdT[(16*j + cl15)*72 + k*32 + kof];
            y[j] = __builtin_amdgcn_mfma_f32_16x16x32_bf16(am, bx, y[j], 0, 0, 0);
        }
    }
    #pragma unroll
    for (int j = 0; j < 4; ++j)
        #pragma unroll
        for (int r = 0; r < 4; ++r)
            ybf[(size_t)(r0 + rbase + r)*DIM + h*HEADDIM + 16*j + cl15] = f2b(y[j][r]);

    // ---- chunk_state[p][n] = sum_l XdT[p][l] * WBT[n][l] -------------------
    f32x4 st[4];
    #pragma unroll
    for (int j = 0; j < 4; ++j) st[j] = (f32x4){0.f,0.f,0.f,0.f};
    #pragma unroll
    for (int k = 0; k < 2; ++k){
        bf16x8 aw = *(const bf16x8*)&XdT[arow*72 + k*32 + kof];
        #pragma unroll
        for (int j = 0; j < 4; ++j){
            bf16x8 bb = *(const bf16x8*)&WBT[(16*j + cl15)*72 + k*32 + kof];
            st[j] = __builtin_amdgcn_mfma_f32_16x16x32_bf16(aw, bb, st[j], 0, 0, 0);
        }
    }
    #pragma unroll
    for (int j = 0; j < 4; ++j)
        #pragma unroll
        for (int r = 0; r < 4; ++r){
            __half hv = __float2half(st[j][r]);
            cstate[(size_t)bid*4096 + (size_t)(rbase + r)*64 + 16*j + cl15] = *(ushort*)&hv;
        }
}

// ---------------------------------------------------------------------------
// K3: inter-chunk scan (f16 states, f32 running sum), emit final_state f32
__global__ __launch_bounds__(256) void k_scan(ushort* __restrict__ cstate,
        const float* __restrict__ css_g, float* __restrict__ fs_out){
    int bid = blockIdx.x;                  // b(2) * h(16) * tile(8)
    int tile = bid & 7, hh = (bid >> 3) & 15, b = bid >> 7;
    int pn = tile*512 + threadIdx.x*2;
    float P0 = 0.f, P1 = 0.f;
    for (int c = 0; c < NCHUNK; ++c){
        size_t base = (size_t)((b*NCHUNK + c)*HEADS + hh);
        float e = __expf(css_g[base*64 + 63]);
        __half2 cur = *(const __half2*)&cstate[base*4096 + pn];
        *( __half2*)&cstate[base*4096 + pn] = __floats2half2_rn(P0, P1);
        float2 cf = __half22float2(cur);
        P0 = e*P0 + cf.x;
        P1 = e*P1 + cf.y;
    }
    *(float2*)&fs_out[(size_t)(b*HEADS + hh)*4096 + pn] = make_float2(P0, P1);
}

// ---------------------------------------------------------------------------
// K4 (f16 MFMA): y += exp(cs[l]) * C·S^T  (bf16 RMW on ybf)
__global__ __launch_bounds__(256) void k_yoff(const float* __restrict__ Cin,
        const ushort* __restrict__ cstate, const float* __restrict__ css_g,
        ushort* __restrict__ ybf){
    int bid = blockIdx.x;
    int h = bid & 15, c = (bid >> 4) & 63, b = bid >> 10;
    int tid = threadIdx.x;
    int lane = tid & 63, wave = tid >> 6;
    int r0 = b*SEQ + c*BLOCKL;
    __shared__ __align__(16) ushort Cs[64*72];   // C rows as f16 [l][n]
    __shared__ __align__(16) ushort Ss[64*72];   // S rows f16 [p][n]
    __shared__ float cse[64];
    {
        int l  = tid >> 2;
        int c0 = (tid & 3) * 16;
        const float* cp = Cin + (size_t)(r0 + l)*DIM + h*DSTATE + c0;
        ushort tc[16];
        #pragma unroll
        for (int q = 0; q < 4; ++q){
            f32x4 vc = *(const f32x4*)(cp + q*4);
            #pragma unroll
            for (int j = 0; j < 4; ++j){
                __half hv = __float2half(vc[j]);
                tc[q*4+j] = *(ushort*)&hv;
            }
        }
        *(uint4*)&Cs[l*72 + c0]     = *(uint4*)&tc[0];
        *(uint4*)&Cs[l*72 + c0 + 8] = *(uint4*)&tc[8];
        const ushort* sp = cstate + (size_t)bid*4096 + (size_t)l*64 + c0;
        *(uint4*)&Ss[l*72 + c0]     = *(const uint4*)sp;
        *(uint4*)&Ss[l*72 + c0 + 8] = *(const uint4*)(sp + 8);
    }
    if (tid < 64) cse[tid] = __expf(css_g[(size_t)bid*64 + tid]);
    __syncthreads();

    int cl15 = lane & 15;
    int g    = lane >> 4;
    int arow = wave*16 + cl15;
    int kof  = g * 8;
    f32x4 acc[4];
    #pragma unroll
    for (int j = 0; j < 4; ++j) acc[j] = (f32x4){0.f,0.f,0.f,0.f};
    #pragma unroll
    for (int k = 0; k < 2; ++k){
        f16x8 a = *(const f16x8*)&Cs[arow*72 + k*32 + kof];
        #pragma unroll
        for (int j = 0; j < 4; ++j){
            f16x8 bb = *(const f16x8*)&Ss[(16*j + cl15)*72 + k*32 + kof];
            acc[j] = __builtin_amdgcn_mfma_f32_16x16x32_f16(a, bb, acc[j], 0, 0, 0);
        }
    }
    int rbase = wave*16 + g*4;
    #pragma unroll
    for (int j = 0; j < 4; ++j)
        #pragma unroll
        for (int r = 0; r < 4; ++r){
            float e = cse[rbase + r];
            size_t idx = (size_t)(r0 + rbase + r)*DIM + h*HEADDIM + 16*j + cl15;
            ybf[idx] = f2b(b2f(ybf[idx]) + e * acc[j][r]);
        }
}

// ---------------------------------------------------------------------------
// K5: LayerNorm over dim (bf16 in, bf16 out, in-place)
__global__ __launch_bounds__(256) void k_ln(ushort* __restrict__ ybf,
        const float* __restrict__ scale, const float* __restrict__ bias){
    int r = blockIdx.x, tid = threadIdx.x;
    ushort* yp = ybf + (size_t)r*DIM + tid*4;
    short4 raw = *(const short4*)yp;
    float v[4];
    v[0] = b2f((ushort)raw.x); v[1] = b2f((ushort)raw.y);
    v[2] = b2f((ushort)raw.z); v[3] = b2f((ushort)raw.w);
    float s1 = v[0]+v[1]+v[2]+v[3];
    float s2 = v[0]*v[0]+v[1]*v[1]+v[2]*v[2]+v[3]*v[3];
    #pragma unroll
    for (int m = 32; m > 0; m >>= 1){
        s1 += __shfl_xor(s1, m, 64);
        s2 += __shfl_xor(s2, m, 64);
    }
    __shared__ float w1[4], w2[4];
    int wv = tid >> 6;
    if ((tid & 63) == 0){ w1[wv] = s1; w2[wv] = s2; }
    __syncthreads();
    float S1 = w1[0]+w1[1]+w1[2]+w1[3];
    float S2 = w2[0]+w2[1]+w2[2]+w2[3];
    float mu  = S1 * (1.f/DIM);
    float var = S2 * (1.f/DIM) - mu*mu;
    float rstd = rsqrtf(var + 1e-6f);
    int d = tid*4;
    f32x4 sc = *(const f32x4*)(scale + d);
    f32x4 bi = *(const f32x4*)(bias + d);
    ushort o[4];
    #pragma unroll
    for (int j = 0; j < 4; ++j)
        o[j] = f2b((v[j] - mu)*rstd*sc[j] + bi[j]);
    *(short4*)yp = *(short4*)&o[0];
}

// ---------------------------------------------------------------------------
// K5b: Wt[n][k] = bf16(W_out[k][n])
__global__ __launch_bounds__(256) void k_wt(const float* __restrict__ W,
        __hip_bfloat16* __restrict__ Wt){
    __shared__ float t[64][65];
    int kt = blockIdx.x >> 4, nt = blockIdx.x & 15;
    int tid = threadIdx.x;
    int lr = tid >> 4, lc4 = (tid & 15) * 4;
    #pragma unroll
    for (int q = 0; q < 4; ++q){
        int k = lr + q*16;
        *(f32x4*)&t[k][lc4] = *(const f32x4*)(W + (size_t)(kt*64 + k)*DIM + nt*64 + lc4);
    }
    __syncthreads();
    #pragma unroll
    for (int q = 0; q < 4; ++q){
        int n = lr + q*16;
        union { __hip_bfloat16 h[4]; short4 s4; } u;
        #pragma unroll
        for (int j = 0; j < 4; ++j) u.h[j] = __float2bfloat16(t[lc4+j][n]);
        *(short4*)((short*)Wt + (size_t)(nt*64 + n)*DIM + kt*64 + lc4) = u.s4;
    }
}

// ---------------------------------------------------------------------------
// K6: Out = yn @ Wt^T (bf16 MFMA, f32 accum), global_load_lds staging
__global__ __launch_bounds__(256) void k_gemm(const __hip_bfloat16* __restrict__ A,
        const __hip_bfloat16* __restrict__ Bt, float* __restrict__ Out){
    __shared__ __align__(16) ushort As[128*32];
    __shared__ __align__(16) ushort Bsh[128*32];
    int bid = blockIdx.x;
    int bn = bid & 7, bm = bid >> 3;
    int tid = threadIdx.x;
    int lane = tid & 63, wave = tid >> 6;
    int wr = wave >> 1, wc = wave & 1;
    f32x4 acc[4][4];
    #pragma unroll
    for (int i = 0; i < 4; ++i)
        #pragma unroll
        for (int j = 0; j < 4; ++j)
            acc[i][j] = (f32x4){0.f, 0.f, 0.f, 0.f};
    const ushort* Ag = (const ushort*)A  + (size_t)bm*128*1024;
    const ushort* Bg = (const ushort*)Bt + (size_t)bn*128*1024;
    int row0 = tid >> 2;
    int col0 = (tid & 3) * 8;
    for (int k0 = 0; k0 < 1024; k0 += 32){
        const ushort* sA = Ag + (size_t)row0*1024 + k0 + col0;
        const ushort* sB = Bg + (size_t)row0*1024 + k0 + col0;
        gload16(sA,           &As[row0*32 + col0]);
        gload16(sA + 64*1024, &As[(row0+64)*32 + col0]);
        gload16(sB,           &Bsh[row0*32 + col0]);
        gload16(sB + 64*1024, &Bsh[(row0+64)*32 + col0]);
        __syncthreads();
        bf16x8 af[4], bfr[4];
        #pragma unroll
        for (int i = 0; i < 4; ++i){
            int arow = wr*64 + i*16 + (lane & 15);
            af[i] = *(const bf16x8*)&As[arow*32 + ((lane >> 4) << 3)];
        }
        #pragma unroll
        for (int j = 0; j < 4; ++j){
            int brow = wc*64 + j*16 + (lane & 15);
            bfr[j] = *(const bf16x8*)&Bsh[brow*32 + ((lane >> 4) << 3)];
        }
        #pragma unroll
        for (int i = 0; i < 4; ++i)
            #pragma unroll
            for (int j = 0; j < 4; ++j)
                acc[i][j] = __builtin_amdgcn_mfma_f32_16x16x32_bf16(af[i], bfr[j], acc[i][j], 0, 0, 0);
        __syncthreads();
    }
    #pragma unroll
    for (int i = 0; i < 4; ++i){
        int m0 = bm*128 + wr*64 + i*16 + ((lane >> 4) << 2);
        #pragma unroll
        for (int j = 0; j < 4; ++j){
            int n = bn*128 + wc*64 + j*16 + (lane & 15);
            #pragma unroll
            for (int reg = 0; reg < 4; ++reg)
                Out[(size_t)(m0 + reg)*1024 + n] = acc[i][j][reg];
        }
    }
}

// ---------------------------------------------------------------------------
extern "C" void kernel_launch(void* const* d_in, const int* in_sizes, int n_in,
                              void* d_out, int out_size, void* d_ws, size_t ws_size,
                              hipStream_t stream){
    const float* X    = (const float*)d_in[0];
    const float* Bin  = (const float*)d_in[1];
    const float* Cin  = (const float*)d_in[2];
    const float* Wdt  = (const float*)d_in[3];
    const float* dtb  = (const float*)d_in[4];
    const float* alog = (const float*)d_in[5];
    const float* Wout = (const float*)d_in[6];
    const float* lns  = (const float*)d_in[7];
    const float* lnb  = (const float*)d_in[8];

    float* out = (float*)d_out;
    float* fs_out = out + (size_t)ROWS*DIM;

    float* dt_g   = (float*)d_ws;                        // 131072 f32
    float* dtA_g  = dt_g  + 131072;                      // 131072 f32
    float* css_g  = dtA_g + 131072;                      // 131072 f32
    ushort* cstate = (ushort*)(css_g + 131072);          // 8388608 f16
    ushort* ybf    = cstate + 8388608;                   // 8388608 bf16 (y -> yn in place)
    __hip_bfloat16* Wt = (__hip_bfloat16*)(ybf + 8388608); // 1048576 bf16

    k_dt   <<<ROWS,               256, 0, stream>>>(X, Wdt, dtb, alog, dt_g, dtA_g);
    k_chunk<<<BATCH*NCHUNK*HEADS, 256, 0, stream>>>(X, Bin, Cin, dt_g, dtA_g, ybf, cstate, css_g);
    k_scan <<<BATCH*HEADS*8,      256, 0, stream>>>(cstate, css_g, fs_out);
    k_yoff <<<BATCH*NCHUNK*HEADS, 256, 0, stream>>>(Cin, cstate, css_g, ybf);
    k_ln   <<<ROWS,               256, 0, stream>>>(ybf, lns, lnb);
    k_wt   <<<256,                256, 0, stream>>>(Wout, Wt);
    k_gemm <<<512,                256, 0, stream>>>((const __hip_bfloat16*)ybf, Wt, out);
}

// Round 8
// 123.046 us; speedup vs baseline: 1.3644x; 1.0323x over previous
//
#include <hip/hip_runtime.h>
#include <hip/hip_bf16.h>
#include <hip/hip_fp16.h>
#include <math.h>

#define BATCH   2
#define SEQ     4096
#define DIM     1024
#define HEADS   16
#define DSTATE  64
#define HEADDIM 64
#define BLOCKL  64
#define NCHUNK  64
#define ROWS    (BATCH*SEQ)

typedef __attribute__((ext_vector_type(4))) float f32x4;
typedef __attribute__((ext_vector_type(8))) short bf16x8;
typedef __attribute__((ext_vector_type(8))) _Float16 f16x8;

static __device__ __forceinline__ float softplus_f(float x){
    return (x > 20.f) ? x : log1pf(__expf(x));
}
static __device__ __forceinline__ ushort f2b(float f){
    __hip_bfloat16 h = __float2bfloat16(f);
    return *reinterpret_cast<ushort*>(&h);
}
static __device__ __forceinline__ float b2f(ushort u){
    uint x = ((uint)u) << 16;
    return *reinterpret_cast<float*>(&x);
}
static __device__ __forceinline__ void gload16(const void* g, void* l){
    __builtin_amdgcn_global_load_lds((const __attribute__((address_space(1))) unsigned int*)g,
                                     (__attribute__((address_space(3))) unsigned int*)l, 16, 0, 0);
}

// ---------------------------------------------------------------------------
// K1 (merged): blocks [0,ROWS): dt/dtA per row.  blocks [ROWS,ROWS+256):
//   Wt[n][k] = bf16(W_out[k][n])  (plain transpose+cast, NO scale folding)
__global__ __launch_bounds__(256) void k_dtwt(const float* __restrict__ X,
        const float* __restrict__ Wdt, const float* __restrict__ dtb,
        const float* __restrict__ alog, const float* __restrict__ W,
        float* __restrict__ dt_g, float* __restrict__ dtA_g,
        ushort* __restrict__ Wt){
    __shared__ float xrow[DIM];
    __shared__ float red[16][17];
    __shared__ float t[64][65];
    int bidx = blockIdx.x;
    int tid = threadIdx.x;
    if (bidx < ROWS){
        int r = bidx;
        int s = r & (SEQ-1);
        *(f32x4*)(xrow + tid*4) = *(const f32x4*)(X + (size_t)r*DIM + tid*4);
        __syncthreads();
        int part = tid >> 4, h = tid & 15;
        int d0 = part * 64;
        float acc = 0.f;
        #pragma unroll 8
        for (int i = 0; i < 64; ++i)
            acc += xrow[d0 + i] * Wdt[(size_t)(d0 + i)*HEADS + h];
        red[part][h] = acc;
        __syncthreads();
        if (tid < 16){
            float sum = 0.f;
            #pragma unroll
            for (int p = 0; p < 16; ++p) sum += red[p][tid];
            sum += dtb[(size_t)s*HEADS + tid];
            float dtv = softplus_f(sum);
            dt_g[(size_t)r*HEADS + tid]  = dtv;
            dtA_g[(size_t)r*HEADS + tid] = -__expf(alog[tid]) * dtv;
        }
    } else {
        int bid = bidx - ROWS;
        int kt = bid >> 4, nt = bid & 15;
        int lr = tid >> 4, lc4 = (tid & 15) * 4;
        #pragma unroll
        for (int q = 0; q < 4; ++q){
            int k = lr + q*16;
            *(f32x4*)&t[k][lc4] = *(const f32x4*)(W + (size_t)(kt*64 + k)*DIM + nt*64 + lc4);
        }
        __syncthreads();
        #pragma unroll
        for (int q = 0; q < 4; ++q){
            int n = lr + q*16;
            ushort o[4];
            #pragma unroll
            for (int j = 0; j < 4; ++j) o[j] = f2b(t[lc4+j][n]);
            *(short4*)(Wt + (size_t)(nt*64 + n)*DIM + kt*64 + lc4) = *(short4*)&o[0];
        }
    }
}

// ---------------------------------------------------------------------------
// K2 (MFMA): G=C·B^T -> M(bf16) ; Y_diag=M·Xd (bf16 out) ; state = Xd^T·(w·B)
// LDS 27.75 KB (region0 reused: {Cs,Bs} -> {Mb,XdT}) -> 5 blocks/CU.
__global__ __launch_bounds__(256) void k_chunk(const float* __restrict__ X,
        const float* __restrict__ Bin, const float* __restrict__ Cin,
        const float* __restrict__ dt_g, const float* __restrict__ dtA_g,
        ushort* __restrict__ ybf, ushort* __restrict__ cstate, float* __restrict__ css_g){
    int bid = blockIdx.x;                  // ((b*64+c)*16+h)
    int h = bid & 15, c = (bid >> 4) & 63, b = bid >> 10;
    int tid = threadIdx.x;
    int lane = tid & 63, wave = tid >> 6;
    int r0 = b*SEQ + c*BLOCKL;

    __shared__ __align__(16) char region0[18432]; // ph1: Cs|Bs  ph2: Mb|XdT
    __shared__ __align__(16) ushort WBT[64*72];   // (w·B)^T [n][l]
    __shared__ float csh[64], dtsh[64], wsh[64];
    ushort* Cs  = (ushort*)region0;            // [64][72] bf16
    ushort* Bs  = (ushort*)(region0 + 9216);   // [64][72] bf16
    ushort* Mb  = (ushort*)region0;            // [64][72] bf16 (after G)
    ushort* XdT = (ushort*)(region0 + 9216);   // [64][72] bf16 (after G)

    int l  = tid >> 2;
    int c0 = (tid & 3) * 16;

    // coalesced row loads into registers
    f32x4 xr[4], br[4], cr[4];
    {
        const float* xp = X   + (size_t)(r0 + l)*DIM + h*HEADDIM + c0;
        const float* bp = Bin + (size_t)(r0 + l)*DIM + h*DSTATE  + c0;
        const float* cp = Cin + (size_t)(r0 + l)*DIM + h*DSTATE  + c0;
        #pragma unroll
        for (int q = 0; q < 4; ++q){
            xr[q] = *(const f32x4*)(xp + q*4);
            br[q] = *(const f32x4*)(bp + q*4);
            cr[q] = *(const f32x4*)(cp + q*4);
        }
    }
    if (tid < 64){
        dtsh[tid] = dt_g[(size_t)(r0 + tid)*HEADS + h];
        float a = dtA_g[(size_t)(r0 + tid)*HEADS + h];
        #pragma unroll
        for (int off = 1; off < 64; off <<= 1){
            float v = __shfl_up(a, off, 64);
            if (tid >= off) a += v;
        }
        csh[tid] = a;
        css_g[(size_t)bid*64 + tid] = a;
        float cs63 = __shfl(a, 63, 64);
        wsh[tid] = __expf(cs63 - a);
    }
    // stage Cs, Bs (row-major bf16)
    {
        ushort tc[16], tb[16];
        #pragma unroll
        for (int q = 0; q < 4; ++q)
            #pragma unroll
            for (int j = 0; j < 4; ++j){
                tc[q*4+j] = f2b(cr[q][j]);
                tb[q*4+j] = f2b(br[q][j]);
            }
        *(uint4*)&Cs[l*72 + c0]     = *(uint4*)&tc[0];
        *(uint4*)&Cs[l*72 + c0 + 8] = *(uint4*)&tc[8];
        *(uint4*)&Bs[l*72 + c0]     = *(uint4*)&tb[0];
        *(uint4*)&Bs[l*72 + c0 + 8] = *(uint4*)&tb[8];
    }
    __syncthreads();            // [sync1] scan + Cs/Bs visible

    int cl15  = lane & 15;
    int g     = lane >> 4;
    int arow  = wave*16 + cl15;
    int kof   = g * 8;
    int rbase = wave*16 + g*4;

    // WBT scatter (doesn't touch region0) overlapped with G MFMA
    {
        float wl = wsh[l];
        #pragma unroll
        for (int q = 0; q < 4; ++q)
            #pragma unroll
            for (int j = 0; j < 4; ++j)
                WBT[(c0 + q*4 + j)*72 + l] = f2b(br[q][j] * wl);
    }
    // ---- G = C·B^T ---------------------------------------------------------
    f32x4 gacc[4];
    #pragma unroll
    for (int j = 0; j < 4; ++j) gacc[j] = (f32x4){0.f,0.f,0.f,0.f};
    #pragma unroll
    for (int k = 0; k < 2; ++k){
        bf16x8 a = *(const bf16x8*)&Cs[arow*72 + k*32 + kof];
        #pragma unroll
        for (int j = 0; j < 4; ++j){
            bf16x8 bb = *(const bf16x8*)&Bs[(16*j + cl15)*72 + k*32 + kof];
            gacc[j] = __builtin_amdgcn_mfma_f32_16x16x32_bf16(a, bb, gacc[j], 0, 0, 0);
        }
    }
    __syncthreads();            // [sync2] Cs/Bs dead; region0 -> Mb|XdT

    // ---- M = tril(G * exp(cs[l]-cs[s])) as bf16 + XdT scatter --------------
    #pragma unroll
    for (int j = 0; j < 4; ++j){
        #pragma unroll
        for (int r = 0; r < 4; ++r){
            int row = rbase + r, col = 16*j + cl15;
            float m = 0.f;
            if (col <= row) m = gacc[j][r] * __expf(csh[row] - csh[col]);
            Mb[row*72 + col] = f2b(m);
        }
    }
    {
        float dl = dtsh[l];
        #pragma unroll
        for (int q = 0; q < 4; ++q)
            #pragma unroll
            for (int j = 0; j < 4; ++j)
                XdT[(c0 + q*4 + j)*72 + l] = f2b(xr[q][j] * dl);
    }
    __syncthreads();            // [sync3]

    // ---- Y_diag = M·Xd (bf16 store) ----------------------------------------
    f32x4 y[4];
    #pragma unroll
    for (int j = 0; j < 4; ++j) y[j] = (f32x4){0.f,0.f,0.f,0.f};
    #pragma unroll
    for (int k = 0; k < 2; ++k){
        bf16x8 am = *(const bf16x8*)&Mb[arow*72 + k*32 + kof];
        #pragma unroll
        for (int j = 0; j < 4; ++j){
            bf16x8 bx = *(const bf16x8*)&XdT[(16*j + cl15)*72 + k*32 + kof];
            y[j] = __builtin_amdgcn_mfma_f32_16x16x32_bf16(am, bx, y[j], 0, 0, 0);
        }
    }
    #pragma unroll
    for (int j = 0; j < 4; ++j)
        #pragma unroll
        for (int r = 0; r < 4; ++r)
            ybf[(size_t)(r0 + rbase + r)*DIM + h*HEADDIM + 16*j + cl15] = f2b(y[j][r]);

    // ---- chunk_state[p][n] = sum_l XdT[p][l] * WBT[n][l] -------------------
    f32x4 st[4];
    #pragma unroll
    for (int j = 0; j < 4; ++j) st[j] = (f32x4){0.f,0.f,0.f,0.f};
    #pragma unroll
    for (int k = 0; k < 2; ++k){
        bf16x8 aw = *(const bf16x8*)&XdT[arow*72 + k*32 + kof];
        #pragma unroll
        for (int j = 0; j < 4; ++j){
            bf16x8 bb = *(const bf16x8*)&WBT[(16*j + cl15)*72 + k*32 + kof];
            st[j] = __builtin_amdgcn_mfma_f32_16x16x32_bf16(aw, bb, st[j], 0, 0, 0);
        }
    }
    #pragma unroll
    for (int j = 0; j < 4; ++j)
        #pragma unroll
        for (int r = 0; r < 4; ++r){
            __half hv = __float2half(st[j][r]);
            cstate[(size_t)bid*4096 + (size_t)(rbase + r)*64 + 16*j + cl15] = *(ushort*)&hv;
        }
}

// ---------------------------------------------------------------------------
// K3: inter-chunk scan (f16 states, f32 running sum), prefetched
__global__ __launch_bounds__(256) void k_scan(ushort* __restrict__ cstate,
        const float* __restrict__ css_g, float* __restrict__ fs_out){
    int bid = blockIdx.x;                  // b(2) * h(16) * tile(8)
    int tile = bid & 7, hh = (bid >> 3) & 15, b = bid >> 7;
    int pn = tile*512 + threadIdx.x*2;
    size_t base0 = (size_t)(b*NCHUNK)*HEADS + hh;
    float P0 = 0.f, P1 = 0.f;
    __half2 cur = *(const __half2*)&cstate[base0*4096 + pn];
    for (int c = 0; c < NCHUNK; ++c){
        size_t base = base0 + (size_t)c*HEADS;
        __half2 nxt = cur;
        if (c < NCHUNK-1) nxt = *(const __half2*)&cstate[(base + HEADS)*4096 + pn];
        float e = __expf(css_g[base*64 + 63]);
        *( __half2*)&cstate[base*4096 + pn] = __floats2half2_rn(P0, P1);
        float2 cf = __half22float2(cur);
        P0 = e*P0 + cf.x;
        P1 = e*P1 + cf.y;
        cur = nxt;
    }
    *(float2*)&fs_out[(size_t)(b*HEADS + hh)*4096 + pn] = make_float2(P0, P1);
}

// ---------------------------------------------------------------------------
// K4 (f16 MFMA): y += exp(cs[l]) * C·S^T  (bf16 RMW on ybf)
__global__ __launch_bounds__(256) void k_yoff(const float* __restrict__ Cin,
        const ushort* __restrict__ cstate, const float* __restrict__ css_g,
        ushort* __restrict__ ybf){
    int bid = blockIdx.x;
    int h = bid & 15, c = (bid >> 4) & 63, b = bid >> 10;
    int tid = threadIdx.x;
    int lane = tid & 63, wave = tid >> 6;
    int r0 = b*SEQ + c*BLOCKL;
    __shared__ __align__(16) ushort Cs[64*72];   // C rows as f16 [l][n]
    __shared__ __align__(16) ushort Ss[64*72];   // S rows f16 [p][n]
    __shared__ float cse[64];
    {
        int l  = tid >> 2;
        int c0 = (tid & 3) * 16;
        const float* cp = Cin + (size_t)(r0 + l)*DIM + h*DSTATE + c0;
        ushort tc[16];
        #pragma unroll
        for (int q = 0; q < 4; ++q){
            f32x4 vc = *(const f32x4*)(cp + q*4);
            #pragma unroll
            for (int j = 0; j < 4; ++j){
                __half hv = __float2half(vc[j]);
                tc[q*4+j] = *(ushort*)&hv;
            }
        }
        *(uint4*)&Cs[l*72 + c0]     = *(uint4*)&tc[0];
        *(uint4*)&Cs[l*72 + c0 + 8] = *(uint4*)&tc[8];
        const ushort* sp = cstate + (size_t)bid*4096 + (size_t)l*64 + c0;
        *(uint4*)&Ss[l*72 + c0]     = *(const uint4*)sp;
        *(uint4*)&Ss[l*72 + c0 + 8] = *(const uint4*)(sp + 8);
    }
    if (tid < 64) cse[tid] = __expf(css_g[(size_t)bid*64 + tid]);
    __syncthreads();

    int cl15 = lane & 15;
    int g    = lane >> 4;
    int arow = wave*16 + cl15;
    int kof  = g * 8;
    f32x4 acc[4];
    #pragma unroll
    for (int j = 0; j < 4; ++j) acc[j] = (f32x4){0.f,0.f,0.f,0.f};
    #pragma unroll
    for (int k = 0; k < 2; ++k){
        f16x8 a = *(const f16x8*)&Cs[arow*72 + k*32 + kof];
        #pragma unroll
        for (int j = 0; j < 4; ++j){
            f16x8 bb = *(const f16x8*)&Ss[(16*j + cl15)*72 + k*32 + kof];
            acc[j] = __builtin_amdgcn_mfma_f32_16x16x32_f16(a, bb, acc[j], 0, 0, 0);
        }
    }
    int rbase = wave*16 + g*4;
    #pragma unroll
    for (int j = 0; j < 4; ++j)
        #pragma unroll
        for (int r = 0; r < 4; ++r){
            float e = cse[rbase + r];
            size_t idx = (size_t)(r0 + rbase + r)*DIM + h*HEADDIM + 16*j + cl15;
            ybf[idx] = f2b(b2f(ybf[idx]) + e * acc[j][r]);
        }
}

// ---------------------------------------------------------------------------
// K5: LayerNorm over dim (bf16 in, bf16 out, in-place)
__global__ __launch_bounds__(256) void k_ln(ushort* __restrict__ ybf,
        const float* __restrict__ scale, const float* __restrict__ bias){
    int r = blockIdx.x, tid = threadIdx.x;
    ushort* yp = ybf + (size_t)r*DIM + tid*4;
    short4 raw = *(const short4*)yp;
    float v[4];
    v[0] = b2f((ushort)raw.x); v[1] = b2f((ushort)raw.y);
    v[2] = b2f((ushort)raw.z); v[3] = b2f((ushort)raw.w);
    float s1 = v[0]+v[1]+v[2]+v[3];
    float s2 = v[0]*v[0]+v[1]*v[1]+v[2]*v[2]+v[3]*v[3];
    #pragma unroll
    for (int m = 32; m > 0; m >>= 1){
        s1 += __shfl_xor(s1, m, 64);
        s2 += __shfl_xor(s2, m, 64);
    }
    __shared__ float w1[4], w2[4];
    int wv = tid >> 6;
    if ((tid & 63) == 0){ w1[wv] = s1; w2[wv] = s2; }
    __syncthreads();
    float S1 = w1[0]+w1[1]+w1[2]+w1[3];
    float S2 = w2[0]+w2[1]+w2[2]+w2[3];
    float mu  = S1 * (1.f/DIM);
    float var = S2 * (1.f/DIM) - mu*mu;
    float rstd = rsqrtf(var + 1e-6f);
    int d = tid*4;
    f32x4 sc = *(const f32x4*)(scale + d);
    f32x4 bi = *(const f32x4*)(bias + d);
    ushort o[4];
    #pragma unroll
    for (int j = 0; j < 4; ++j)
        o[j] = f2b((v[j] - mu)*rstd*sc[j] + bi[j]);
    *(short4*)yp = *(short4*)&o[0];
}

// ---------------------------------------------------------------------------
// K6: Out = yn @ Wt^T (bf16 MFMA, f32 accum), gload16 staging + XCD swizzle
__global__ __launch_bounds__(256) void k_gemm(const ushort* __restrict__ A,
        const ushort* __restrict__ Bt, float* __restrict__ Out){
    __shared__ __align__(16) ushort As[128*32];
    __shared__ __align__(16) ushort Bsh[128*32];
    int bid = blockIdx.x;
    int wgid = (bid & 7)*64 + (bid >> 3);      // XCD swizzle (512 = 8 XCD * 64)
    int bn = wgid & 7, bm = wgid >> 3;
    int tid = threadIdx.x;
    int lane = tid & 63, wave = tid >> 6;
    int wr = wave >> 1, wc = wave & 1;
    f32x4 acc[4][4];
    #pragma unroll
    for (int i = 0; i < 4; ++i)
        #pragma unroll
        for (int j = 0; j < 4; ++j)
            acc[i][j] = (f32x4){0.f, 0.f, 0.f, 0.f};
    const ushort* Ag = A  + (size_t)bm*128*1024;
    const ushort* Bg = Bt + (size_t)bn*128*1024;
    int row0 = tid >> 2;
    int col0 = (tid & 3) * 8;
    for (int k0 = 0; k0 < 1024; k0 += 32){
        const ushort* sA = Ag + (size_t)row0*1024 + k0 + col0;
        const ushort* sB = Bg + (size_t)row0*1024 + k0 + col0;
        gload16(sA,           &As[row0*32 + col0]);
        gload16(sA + 64*1024, &As[(row0+64)*32 + col0]);
        gload16(sB,           &Bsh[row0*32 + col0]);
        gload16(sB + 64*1024, &Bsh[(row0+64)*32 + col0]);
        __syncthreads();
        bf16x8 af[4], bfr[4];
        #pragma unroll
        for (int i = 0; i < 4; ++i){
            int arow = wr*64 + i*16 + (lane & 15);
            af[i] = *(const bf16x8*)&As[arow*32 + ((lane >> 4) << 3)];
        }
        #pragma unroll
        for (int j = 0; j < 4; ++j){
            int brow = wc*64 + j*16 + (lane & 15);
            bfr[j] = *(const bf16x8*)&Bsh[brow*32 + ((lane >> 4) << 3)];
        }
        #pragma unroll
        for (int i = 0; i < 4; ++i)
            #pragma unroll
            for (int j = 0; j < 4; ++j)
                acc[i][j] = __builtin_amdgcn_mfma_f32_16x16x32_bf16(af[i], bfr[j], acc[i][j], 0, 0, 0);
        __syncthreads();
    }
    #pragma unroll
    for (int i = 0; i < 4; ++i){
        int m0 = bm*128 + wr*64 + i*16 + ((lane >> 4) << 2);
        #pragma unroll
        for (int j = 0; j < 4; ++j){
            int n = bn*128 + wc*64 + j*16 + (lane & 15);
            #pragma unroll
            for (int reg = 0; reg < 4; ++reg)
                Out[(size_t)(m0 + reg)*1024 + n] = acc[i][j][reg];
        }
    }
}

// ---------------------------------------------------------------------------
extern "C" void kernel_launch(void* const* d_in, const int* in_sizes, int n_in,
                              void* d_out, int out_size, void* d_ws, size_t ws_size,
                              hipStream_t stream){
    const float* X    = (const float*)d_in[0];
    const float* Bin  = (const float*)d_in[1];
    const float* Cin  = (const float*)d_in[2];
    const float* Wdt  = (const float*)d_in[3];
    const float* dtb  = (const float*)d_in[4];
    const float* alog = (const float*)d_in[5];
    const float* Wout = (const float*)d_in[6];
    const float* lns  = (const float*)d_in[7];
    const float* lnb  = (const float*)d_in[8];

    float* out = (float*)d_out;
    float* fs_out = out + (size_t)ROWS*DIM;

    char* ws = (char*)d_ws;
    float*  dt_g   = (float*)(ws);                         // 0.5 MB
    float*  dtA_g  = (float*)(ws + 524288);                // 0.5 MB
    float*  css_g  = (float*)(ws + 1048576);               // 0.5 MB
    ushort* cstate = (ushort*)(ws + 1572864);              // 16 MB  f16
    ushort* ybf    = (ushort*)(ws + 18350080);             // 16 MB  bf16 (y -> yn in place)
    ushort* Wt     = (ushort*)(ws + 35127296);             // 2 MB   bf16

    k_dtwt <<<ROWS + 256,         256, 0, stream>>>(X, Wdt, dtb, alog, Wout, dt_g, dtA_g, Wt);
    k_chunk<<<BATCH*NCHUNK*HEADS, 256, 0, stream>>>(X, Bin, Cin, dt_g, dtA_g, ybf, cstate, css_g);
    k_scan <<<BATCH*HEADS*8,      256, 0, stream>>>(cstate, css_g, fs_out);
    k_yoff <<<BATCH*NCHUNK*HEADS, 256, 0, stream>>>(Cin, cstate, css_g, ybf);
    k_ln   <<<ROWS,               256, 0, stream>>>(ybf, lns, lnb);
    k_gemm <<<512,                256, 0, stream>>>(ybf, Wt, out);
}

// Round 9
// 121.289 us; speedup vs baseline: 1.3841x; 1.0145x over previous
//
#include <hip/hip_runtime.h>
#include <hip/hip_bf16.h>
#include <hip/hip_fp16.h>
#include <math.h>

#define BATCH   2
#define SEQ     4096
#define DIM     1024
#define HEADS   16
#define DSTATE  64
#define HEADDIM 64
#define BLOCKL  64
#define NCHUNK  64
#define ROWS    (BATCH*SEQ)

typedef __attribute__((ext_vector_type(4))) float f32x4;
typedef __attribute__((ext_vector_type(8))) short bf16x8;
typedef __attribute__((ext_vector_type(8))) _Float16 f16x8;

static __device__ __forceinline__ float softplus_f(float x){
    return (x > 20.f) ? x : log1pf(__expf(x));
}
static __device__ __forceinline__ ushort f2b(float f){
    __hip_bfloat16 h = __float2bfloat16(f);
    return *reinterpret_cast<ushort*>(&h);
}
static __device__ __forceinline__ float b2f(ushort u){
    uint x = ((uint)u) << 16;
    return *reinterpret_cast<float*>(&x);
}
static __device__ __forceinline__ void gload16(const void* g, void* l){
    __builtin_amdgcn_global_load_lds((const __attribute__((address_space(1))) unsigned int*)g,
                                     (__attribute__((address_space(3))) unsigned int*)l, 16, 0, 0);
}

// ---------------------------------------------------------------------------
// K1 (merged): blocks [0,ROWS): dt/dtA per row.  blocks [ROWS,ROWS+256):
//   Wt[n][k] = bf16(W_out[k][n])
__global__ __launch_bounds__(256) void k_dtwt(const float* __restrict__ X,
        const float* __restrict__ Wdt, const float* __restrict__ dtb,
        const float* __restrict__ alog, const float* __restrict__ W,
        float* __restrict__ dt_g, float* __restrict__ dtA_g,
        ushort* __restrict__ Wt){
    __shared__ float xrow[DIM];
    __shared__ float red[16][17];
    __shared__ float t[64][65];
    int bidx = blockIdx.x;
    int tid = threadIdx.x;
    if (bidx < ROWS){
        int r = bidx;
        int s = r & (SEQ-1);
        *(f32x4*)(xrow + tid*4) = *(const f32x4*)(X + (size_t)r*DIM + tid*4);
        __syncthreads();
        int part = tid >> 4, h = tid & 15;
        int d0 = part * 64;
        float acc = 0.f;
        #pragma unroll 8
        for (int i = 0; i < 64; ++i)
            acc += xrow[d0 + i] * Wdt[(size_t)(d0 + i)*HEADS + h];
        red[part][h] = acc;
        __syncthreads();
        if (tid < 16){
            float sum = 0.f;
            #pragma unroll
            for (int p = 0; p < 16; ++p) sum += red[p][tid];
            sum += dtb[(size_t)s*HEADS + tid];
            float dtv = softplus_f(sum);
            dt_g[(size_t)r*HEADS + tid]  = dtv;
            dtA_g[(size_t)r*HEADS + tid] = -__expf(alog[tid]) * dtv;
        }
    } else {
        int bid = bidx - ROWS;
        int kt = bid >> 4, nt = bid & 15;
        int lr = tid >> 4, lc4 = (tid & 15) * 4;
        #pragma unroll
        for (int q = 0; q < 4; ++q){
            int k = lr + q*16;
            *(f32x4*)&t[k][lc4] = *(const f32x4*)(W + (size_t)(kt*64 + k)*DIM + nt*64 + lc4);
        }
        __syncthreads();
        #pragma unroll
        for (int q = 0; q < 4; ++q){
            int n = lr + q*16;
            ushort o[4];
            #pragma unroll
            for (int j = 0; j < 4; ++j) o[j] = f2b(t[lc4+j][n]);
            *(short4*)(Wt + (size_t)(nt*64 + n)*DIM + kt*64 + lc4) = *(short4*)&o[0];
        }
    }
}

// ---------------------------------------------------------------------------
// K2 (MFMA): G=C·B^T -> M(bf16) ; Y_diag=M·Xd (bf16 out) ; state = Xd^T·(w·B)
// LDS 27.75 KB (region0 reused: {Cs,Bs} -> {Mb,XdT}) -> 5 blocks/CU.
__global__ __launch_bounds__(256) void k_chunk(const float* __restrict__ X,
        const float* __restrict__ Bin, const float* __restrict__ Cin,
        const float* __restrict__ dt_g, const float* __restrict__ dtA_g,
        ushort* __restrict__ ybf, ushort* __restrict__ cstate, float* __restrict__ css_g){
    int bid = blockIdx.x;                  // ((b*64+c)*16+h)
    int h = bid & 15, c = (bid >> 4) & 63, b = bid >> 10;
    int tid = threadIdx.x;
    int lane = tid & 63, wave = tid >> 6;
    int r0 = b*SEQ + c*BLOCKL;

    __shared__ __align__(16) char region0[18432]; // ph1: Cs|Bs  ph2: Mb|XdT
    __shared__ __align__(16) ushort WBT[64*72];   // (w·B)^T [n][l]
    __shared__ float csh[64], dtsh[64], wsh[64];
    ushort* Cs  = (ushort*)region0;            // [64][72] bf16
    ushort* Bs  = (ushort*)(region0 + 9216);   // [64][72] bf16
    ushort* Mb  = (ushort*)region0;            // [64][72] bf16 (after G)
    ushort* XdT = (ushort*)(region0 + 9216);   // [64][72] bf16 (after G)

    int l  = tid >> 2;
    int c0 = (tid & 3) * 16;

    f32x4 xr[4], br[4], cr[4];
    {
        const float* xp = X   + (size_t)(r0 + l)*DIM + h*HEADDIM + c0;
        const float* bp = Bin + (size_t)(r0 + l)*DIM + h*DSTATE  + c0;
        const float* cp = Cin + (size_t)(r0 + l)*DIM + h*DSTATE  + c0;
        #pragma unroll
        for (int q = 0; q < 4; ++q){
            xr[q] = *(const f32x4*)(xp + q*4);
            br[q] = *(const f32x4*)(bp + q*4);
            cr[q] = *(const f32x4*)(cp + q*4);
        }
    }
    if (tid < 64){
        dtsh[tid] = dt_g[(size_t)(r0 + tid)*HEADS + h];
        float a = dtA_g[(size_t)(r0 + tid)*HEADS + h];
        #pragma unroll
        for (int off = 1; off < 64; off <<= 1){
            float v = __shfl_up(a, off, 64);
            if (tid >= off) a += v;
        }
        csh[tid] = a;
        css_g[(size_t)bid*64 + tid] = a;
        float cs63 = __shfl(a, 63, 64);
        wsh[tid] = __expf(cs63 - a);
    }
    {
        ushort tc[16], tb[16];
        #pragma unroll
        for (int q = 0; q < 4; ++q)
            #pragma unroll
            for (int j = 0; j < 4; ++j){
                tc[q*4+j] = f2b(cr[q][j]);
                tb[q*4+j] = f2b(br[q][j]);
            }
        *(uint4*)&Cs[l*72 + c0]     = *(uint4*)&tc[0];
        *(uint4*)&Cs[l*72 + c0 + 8] = *(uint4*)&tc[8];
        *(uint4*)&Bs[l*72 + c0]     = *(uint4*)&tb[0];
        *(uint4*)&Bs[l*72 + c0 + 8] = *(uint4*)&tb[8];
    }
    __syncthreads();            // [sync1]

    int cl15  = lane & 15;
    int g     = lane >> 4;
    int arow  = wave*16 + cl15;
    int kof   = g * 8;
    int rbase = wave*16 + g*4;

    // WBT scatter (separate LDS region) overlapped with G MFMA
    {
        float wl = wsh[l];
        #pragma unroll
        for (int q = 0; q < 4; ++q)
            #pragma unroll
            for (int j = 0; j < 4; ++j)
                WBT[(c0 + q*4 + j)*72 + l] = f2b(br[q][j] * wl);
    }
    f32x4 gacc[4];
    #pragma unroll
    for (int j = 0; j < 4; ++j) gacc[j] = (f32x4){0.f,0.f,0.f,0.f};
    #pragma unroll
    for (int k = 0; k < 2; ++k){
        bf16x8 a = *(const bf16x8*)&Cs[arow*72 + k*32 + kof];
        #pragma unroll
        for (int j = 0; j < 4; ++j){
            bf16x8 bb = *(const bf16x8*)&Bs[(16*j + cl15)*72 + k*32 + kof];
            gacc[j] = __builtin_amdgcn_mfma_f32_16x16x32_bf16(a, bb, gacc[j], 0, 0, 0);
        }
    }
    __syncthreads();            // [sync2] region0 -> Mb|XdT

    #pragma unroll
    for (int j = 0; j < 4; ++j){
        #pragma unroll
        for (int r = 0; r < 4; ++r){
            int row = rbase + r, col = 16*j + cl15;
            float m = 0.f;
            if (col <= row) m = gacc[j][r] * __expf(csh[row] - csh[col]);
            Mb[row*72 + col] = f2b(m);
        }
    }
    {
        float dl = dtsh[l];
        #pragma unroll
        for (int q = 0; q < 4; ++q)
            #pragma unroll
            for (int j = 0; j < 4; ++j)
                XdT[(c0 + q*4 + j)*72 + l] = f2b(xr[q][j] * dl);
    }
    __syncthreads();            // [sync3]

    f32x4 y[4];
    #pragma unroll
    for (int j = 0; j < 4; ++j) y[j] = (f32x4){0.f,0.f,0.f,0.f};
    #pragma unroll
    for (int k = 0; k < 2; ++k){
        bf16x8 am = *(const bf16x8*)&Mb[arow*72 + k*32 + kof];
        #pragma unroll
        for (int j = 0; j < 4; ++j){
            bf16x8 bx = *(const bf16x8*)&XdT[(16*j + cl15)*72 + k*32 + kof];
            y[j] = __builtin_amdgcn_mfma_f32_16x16x32_bf16(am, bx, y[j], 0, 0, 0);
        }
    }
    #pragma unroll
    for (int j = 0; j < 4; ++j)
        #pragma unroll
        for (int r = 0; r < 4; ++r)
            ybf[(size_t)(r0 + rbase + r)*DIM + h*HEADDIM + 16*j + cl15] = f2b(y[j][r]);

    f32x4 st[4];
    #pragma unroll
    for (int j = 0; j < 4; ++j) st[j] = (f32x4){0.f,0.f,0.f,0.f};
    #pragma unroll
    for (int k = 0; k < 2; ++k){
        bf16x8 aw = *(const bf16x8*)&XdT[arow*72 + k*32 + kof];
        #pragma unroll
        for (int j = 0; j < 4; ++j){
            bf16x8 bb = *(const bf16x8*)&WBT[(16*j + cl15)*72 + k*32 + kof];
            st[j] = __builtin_amdgcn_mfma_f32_16x16x32_bf16(aw, bb, st[j], 0, 0, 0);
        }
    }
    #pragma unroll
    for (int j = 0; j < 4; ++j)
        #pragma unroll
        for (int r = 0; r < 4; ++r){
            __half hv = __float2half(st[j][r]);
            cstate[(size_t)bid*4096 + (size_t)(rbase + r)*64 + 16*j + cl15] = *(ushort*)&hv;
        }
}

// ---------------------------------------------------------------------------
// K3: inter-chunk scan. Decay factors preloaded to LDS; prefetch depth 2.
__global__ __launch_bounds__(256) void k_scan(ushort* __restrict__ cstate,
        const float* __restrict__ css_g, float* __restrict__ fs_out){
    int bid = blockIdx.x;                  // b(2) * h(16) * tile(8)
    int tile = bid & 7, hh = (bid >> 3) & 15, b = bid >> 7;
    int tid = threadIdx.x;
    int pn = tile*512 + tid*2;
    size_t base0 = (size_t)(b*NCHUNK)*HEADS + hh;
    __shared__ float esh[64];
    if (tid < 64)
        esh[tid] = __expf(css_g[(base0 + (size_t)tid*HEADS)*64 + 63]);
    __syncthreads();
    ushort* p0 = cstate + base0*4096 + pn;
    const size_t cstep = (size_t)HEADS*4096;
    float P0 = 0.f, P1 = 0.f;
    __half2 cur = *(const __half2*)p0;
    __half2 nxt = *(const __half2*)(p0 + cstep);
    for (int c = 0; c < NCHUNK; ++c){
        __half2 fut = nxt;
        if (c + 2 < NCHUNK) fut = *(const __half2*)(p0 + (size_t)(c+2)*cstep);
        *( __half2*)(p0 + (size_t)c*cstep) = __floats2half2_rn(P0, P1);
        float2 cf = __half22float2(cur);
        float e = esh[c];
        P0 = e*P0 + cf.x;
        P1 = e*P1 + cf.y;
        cur = nxt;
        nxt = fut;
    }
    *(float2*)&fs_out[(size_t)(b*HEADS + hh)*4096 + pn] = make_float2(P0, P1);
}

// ---------------------------------------------------------------------------
// K4 (f16 MFMA): y += exp(cs[l]) * C·S^T  (bf16 RMW on ybf)
__global__ __launch_bounds__(256) void k_yoff(const float* __restrict__ Cin,
        const ushort* __restrict__ cstate, const float* __restrict__ css_g,
        ushort* __restrict__ ybf){
    int bid = blockIdx.x;
    int h = bid & 15, c = (bid >> 4) & 63, b = bid >> 10;
    int tid = threadIdx.x;
    int lane = tid & 63, wave = tid >> 6;
    int r0 = b*SEQ + c*BLOCKL;
    __shared__ __align__(16) ushort Cs[64*72];
    __shared__ __align__(16) ushort Ss[64*72];
    __shared__ float cse[64];
    {
        int l  = tid >> 2;
        int c0 = (tid & 3) * 16;
        const float* cp = Cin + (size_t)(r0 + l)*DIM + h*DSTATE + c0;
        ushort tc[16];
        #pragma unroll
        for (int q = 0; q < 4; ++q){
            f32x4 vc = *(const f32x4*)(cp + q*4);
            #pragma unroll
            for (int j = 0; j < 4; ++j){
                __half hv = __float2half(vc[j]);
                tc[q*4+j] = *(ushort*)&hv;
            }
        }
        *(uint4*)&Cs[l*72 + c0]     = *(uint4*)&tc[0];
        *(uint4*)&Cs[l*72 + c0 + 8] = *(uint4*)&tc[8];
        const ushort* sp = cstate + (size_t)bid*4096 + (size_t)l*64 + c0;
        *(uint4*)&Ss[l*72 + c0]     = *(const uint4*)sp;
        *(uint4*)&Ss[l*72 + c0 + 8] = *(const uint4*)(sp + 8);
    }
    if (tid < 64) cse[tid] = __expf(css_g[(size_t)bid*64 + tid]);
    __syncthreads();

    int cl15 = lane & 15;
    int g    = lane >> 4;
    int arow = wave*16 + cl15;
    int kof  = g * 8;
    f32x4 acc[4];
    #pragma unroll
    for (int j = 0; j < 4; ++j) acc[j] = (f32x4){0.f,0.f,0.f,0.f};
    #pragma unroll
    for (int k = 0; k < 2; ++k){
        f16x8 a = *(const f16x8*)&Cs[arow*72 + k*32 + kof];
        #pragma unroll
        for (int j = 0; j < 4; ++j){
            f16x8 bb = *(const f16x8*)&Ss[(16*j + cl15)*72 + k*32 + kof];
            acc[j] = __builtin_amdgcn_mfma_f32_16x16x32_f16(a, bb, acc[j], 0, 0, 0);
        }
    }
    int rbase = wave*16 + g*4;
    #pragma unroll
    for (int j = 0; j < 4; ++j)
        #pragma unroll
        for (int r = 0; r < 4; ++r){
            float e = cse[rbase + r];
            size_t idx = (size_t)(r0 + rbase + r)*DIM + h*HEADDIM + 16*j + cl15;
            ybf[idx] = f2b(b2f(ybf[idx]) + e * acc[j][r]);
        }
}

// ---------------------------------------------------------------------------
// K5: LayerNorm over dim (bf16 in, bf16 out, in-place)
__global__ __launch_bounds__(256) void k_ln(ushort* __restrict__ ybf,
        const float* __restrict__ scale, const float* __restrict__ bias){
    int r = blockIdx.x, tid = threadIdx.x;
    ushort* yp = ybf + (size_t)r*DIM + tid*4;
    short4 raw = *(const short4*)yp;
    float v[4];
    v[0] = b2f((ushort)raw.x); v[1] = b2f((ushort)raw.y);
    v[2] = b2f((ushort)raw.z); v[3] = b2f((ushort)raw.w);
    float s1 = v[0]+v[1]+v[2]+v[3];
    float s2 = v[0]*v[0]+v[1]*v[1]+v[2]*v[2]+v[3]*v[3];
    #pragma unroll
    for (int m = 32; m > 0; m >>= 1){
        s1 += __shfl_xor(s1, m, 64);
        s2 += __shfl_xor(s2, m, 64);
    }
    __shared__ float w1[4], w2[4];
    int wv = tid >> 6;
    if ((tid & 63) == 0){ w1[wv] = s1; w2[wv] = s2; }
    __syncthreads();
    float S1 = w1[0]+w1[1]+w1[2]+w1[3];
    float S2 = w2[0]+w2[1]+w2[2]+w2[3];
    float mu  = S1 * (1.f/DIM);
    float var = S2 * (1.f/DIM) - mu*mu;
    float rstd = rsqrtf(var + 1e-6f);
    int d = tid*4;
    f32x4 sc = *(const f32x4*)(scale + d);
    f32x4 bi = *(const f32x4*)(bias + d);
    ushort o[4];
    #pragma unroll
    for (int j = 0; j < 4; ++j)
        o[j] = f2b((v[j] - mu)*rstd*sc[j] + bi[j]);
    *(short4*)yp = *(short4*)&o[0];
}

// ---------------------------------------------------------------------------
// K6: Out = yn @ Wt^T.  64x128 tile, grid 1024 (4 blocks/CU), XCD swizzle.
__global__ __launch_bounds__(256) void k_gemm(const ushort* __restrict__ A,
        const ushort* __restrict__ Bt, float* __restrict__ Out){
    __shared__ __align__(16) ushort As[64*32];    // 4 KB
    __shared__ __align__(16) ushort Bsh[128*32];  // 8 KB
    int bid = blockIdx.x;
    int wgid = (bid & 7)*128 + (bid >> 3);        // XCD swizzle (1024 = 8*128)
    int bn = wgid & 7, bm = wgid >> 3;            // bm 0..127, bn 0..7
    int tid = threadIdx.x;
    int lane = tid & 63, wave = tid >> 6;
    int wr = wave >> 1, wc = wave & 1;            // 2x2 waves: 32 rows x 64 cols each
    f32x4 acc[2][4];
    #pragma unroll
    for (int i = 0; i < 2; ++i)
        #pragma unroll
        for (int j = 0; j < 4; ++j)
            acc[i][j] = (f32x4){0.f, 0.f, 0.f, 0.f};
    const ushort* Ag = A  + (size_t)bm*64*1024;
    const ushort* Bg = Bt + (size_t)bn*128*1024;
    int row0 = tid >> 2;                          // 0..63
    int col0 = (tid & 3) * 8;
    for (int k0 = 0; k0 < 1024; k0 += 32){
        const ushort* sA = Ag + (size_t)row0*1024 + k0 + col0;
        const ushort* sB = Bg + (size_t)row0*1024 + k0 + col0;
        gload16(sA,           &As[row0*32 + col0]);
        gload16(sB,           &Bsh[row0*32 + col0]);
        gload16(sB + 64*1024, &Bsh[(row0+64)*32 + col0]);
        __syncthreads();
        bf16x8 af[2], bfr[4];
        #pragma unroll
        for (int i = 0; i < 2; ++i){
            int arow = wr*32 + i*16 + (lane & 15);
            af[i] = *(const bf16x8*)&As[arow*32 + ((lane >> 4) << 3)];
        }
        #pragma unroll
        for (int j = 0; j < 4; ++j){
            int brow = wc*64 + j*16 + (lane & 15);
            bfr[j] = *(const bf16x8*)&Bsh[brow*32 + ((lane >> 4) << 3)];
        }
        #pragma unroll
        for (int i = 0; i < 2; ++i)
            #pragma unroll
            for (int j = 0; j < 4; ++j)
                acc[i][j] = __builtin_amdgcn_mfma_f32_16x16x32_bf16(af[i], bfr[j], acc[i][j], 0, 0, 0);
        __syncthreads();
    }
    #pragma unroll
    for (int i = 0; i < 2; ++i){
        int m0 = bm*64 + wr*32 + i*16 + ((lane >> 4) << 2);
        #pragma unroll
        for (int j = 0; j < 4; ++j){
            int n = bn*128 + wc*64 + j*16 + (lane & 15);
            #pragma unroll
            for (int reg = 0; reg < 4; ++reg)
                Out[(size_t)(m0 + reg)*1024 + n] = acc[i][j][reg];
        }
    }
}

// ---------------------------------------------------------------------------
extern "C" void kernel_launch(void* const* d_in, const int* in_sizes, int n_in,
                              void* d_out, int out_size, void* d_ws, size_t ws_size,
                              hipStream_t stream){
    const float* X    = (const float*)d_in[0];
    const float* Bin  = (const float*)d_in[1];
    const float* Cin  = (const float*)d_in[2];
    const float* Wdt  = (const float*)d_in[3];
    const float* dtb  = (const float*)d_in[4];
    const float* alog = (const float*)d_in[5];
    const float* Wout = (const float*)d_in[6];
    const float* lns  = (const float*)d_in[7];
    const float* lnb  = (const float*)d_in[8];

    float* out = (float*)d_out;
    float* fs_out = out + (size_t)ROWS*DIM;

    char* ws = (char*)d_ws;
    float*  dt_g   = (float*)(ws);                         // 0.5 MB
    float*  dtA_g  = (float*)(ws + 524288);                // 0.5 MB
    float*  css_g  = (float*)(ws + 1048576);               // 0.5 MB
    ushort* cstate = (ushort*)(ws + 1572864);              // 16 MB  f16
    ushort* ybf    = (ushort*)(ws + 18350080);             // 16 MB  bf16 (y -> yn in place)
    ushort* Wt     = (ushort*)(ws + 35127296);             // 2 MB   bf16

    k_dtwt <<<ROWS + 256,         256, 0, stream>>>(X, Wdt, dtb, alog, Wout, dt_g, dtA_g, Wt);
    k_chunk<<<BATCH*NCHUNK*HEADS, 256, 0, stream>>>(X, Bin, Cin, dt_g, dtA_g, ybf, cstate, css_g);
    k_scan <<<BATCH*HEADS*8,      256, 0, stream>>>(cstate, css_g, fs_out);
    k_yoff <<<BATCH*NCHUNK*HEADS, 256, 0, stream>>>(Cin, cstate, css_g, ybf);
    k_ln   <<<ROWS,               256, 0, stream>>>(ybf, lns, lnb);
    k_gemm <<<1024,               256, 0, stream>>>(ybf, Wt, out);
}